// Round 11
// baseline (139.215 us; speedup 1.0000x reference)
//
#include <hip/hip_runtime.h>
#include <hip/hip_bf16.h>
#include <stdint.h>

typedef float f32x4 __attribute__((ext_vector_type(4)));
typedef float f32x4v __attribute__((ext_vector_type(4)));
typedef __bf16 bf16x8 __attribute__((ext_vector_type(8)));
typedef __bf16 bf16x4 __attribute__((ext_vector_type(4)));
typedef __bf16 bf16x2 __attribute__((ext_vector_type(2)));
typedef unsigned int u32x4 __attribute__((ext_vector_type(4)));

#define LOG2E 1.44269504088896340736f
#define MFMA16(a, b, c) __builtin_amdgcn_mfma_f32_16x16x32_bf16((a), (b), (c), 0, 0, 0)

static __device__ __forceinline__ void gload_lds16(const void* g, void* l) {
  __builtin_amdgcn_global_load_lds(
      (const __attribute__((address_space(1))) unsigned int*)g,
      (__attribute__((address_space(3))) unsigned int*)l, 16, 0, 0);
}

static __device__ __forceinline__ uint32_t pk2(float lo, float hi) {
  bf16x2 v;
  v[0] = (__bf16)lo;
  v[1] = (__bf16)hi;
  return __builtin_bit_cast(uint32_t, v);
}

// ---------------------------------------------------------------- prep: cvt + both transposes
// blocks [0,4096): x f32->bf16 ; [4096,5632): wqkv transpose ; [5632,6656): wo transpose
__global__ __launch_bounds__(256) void prep(const float* __restrict__ x,
                                            __bf16* __restrict__ xb,
                                            const float* __restrict__ wqkv,
                                            __bf16* __restrict__ wqkvT,
                                            const float* __restrict__ wo,
                                            __bf16* __restrict__ woT) {
  __shared__ float tile[64][65];
  int b = blockIdx.x;
  int t = threadIdx.x;
  if (b < 4096) {
    int i = b * 256 + t;
    f32x4v v = *(const f32x4v*)(x + (size_t)i * 4);
    bf16x4 o;
    o[0] = (__bf16)v[0]; o[1] = (__bf16)v[1]; o[2] = (__bf16)v[2]; o[3] = (__bf16)v[3];
    *(bf16x4*)(xb + (size_t)i * 4) = o;
    return;
  }
  const float* in;
  __bf16* out;
  int R, C, bx, by;
  if (b < 5632) {
    int bb = b - 4096;
    in = wqkv; out = wqkvT; R = 2048; C = 3072; bx = bb % 48; by = bb / 48;
  } else {
    int bb = b - 5632;
    in = wo; out = woT; R = 2048; C = 2048; bx = bb & 31; by = bb >> 5;
  }
  int tr = by * 64, tc = bx * 64;
  int r0 = t >> 4;
  int c4 = (t & 15) * 4;
#pragma unroll
  for (int i = 0; i < 4; ++i) {
    int r = r0 + i * 16;
    f32x4v v = *(const f32x4v*)(in + (size_t)(tr + r) * C + tc + c4);
    tile[r][c4 + 0] = v[0]; tile[r][c4 + 1] = v[1];
    tile[r][c4 + 2] = v[2]; tile[r][c4 + 3] = v[3];
  }
  __syncthreads();
#pragma unroll
  for (int i = 0; i < 4; ++i) {
    int r = r0 + i * 16;
    __bf16* o = out + (size_t)(tc + r) * R + tr + c4;
    bf16x4 ov;
    ov[0] = (__bf16)tile[c4 + 0][r]; ov[1] = (__bf16)tile[c4 + 1][r];
    ov[2] = (__bf16)tile[c4 + 2][r]; ov[3] = (__bf16)tile[c4 + 3][r];
    *(bf16x4*)o = ov;
  }
}

// ---------------------------------------------------------------- GEMM: 8-wave (512t),
// 128x128 tile, BK=64, 1-barrier dbuf, XOR-swizzled LDS, XCD swizzle (gx%8==0).
// Split-K via blockIdx.z (kSplit elems per z); ATOMIC accumulates f32 into C.
template <typename OutT, bool ATOMIC>
__global__ __launch_bounds__(512) void gemm8w(const __bf16* __restrict__ A,
                                              const __bf16* __restrict__ BT,
                                              OutT* __restrict__ C,
                                              int M, int N, int K, int kSplit) {
  __shared__ alignas(16) __bf16 As[2][128 * 64];
  __shared__ alignas(16) __bf16 Bs[2][128 * 64];
  int gx = gridDim.x;
  int l = blockIdx.y * gx + blockIdx.x;
  int cpx = gx >> 3;
  int xcd = l & 7, rr0 = l >> 3;
  int bn = xcd * cpx + rr0 % cpx;
  int bm = rr0 / cpx;
  int kBeg = blockIdx.z * kSplit;
  int t = threadIdx.x;
  int lane = t & 63, w = t >> 6;  // 8 waves
  int lmod = lane & 15, ldiv = lane >> 4;
  int wr = w >> 1, wc = w & 1;

  f32x4 acc[2][4] = {};

  int sr8 = lane >> 3;
  int sk = (lane & 7) ^ sr8;  // pre-swizzled global source chunk
  const __bf16* gaB[2];
  const __bf16* gbB[2];
#pragma unroll
  for (int c = 0; c < 2; ++c) {
    int rr = (2 * w + c) * 8 + sr8;
    gaB[c] = A + (size_t)(bm * 128 + rr) * K + kBeg + sk * 8;
    gbB[c] = BT + (size_t)(bn * 128 + rr) * K + kBeg + sk * 8;
  }

#define GSTAGE(buf, k0)                                                \
  {                                                                    \
    _Pragma("unroll") for (int c = 0; c < 2; ++c) {                    \
      gload_lds16(gaB[c] + (k0), &As[buf][(2 * w + c) * 512]);         \
      gload_lds16(gbB[c] + (k0), &Bs[buf][(2 * w + c) * 512]);         \
    }                                                                  \
  }

  int ca = ldiv ^ (lmod & 7);        // swizzled chunk, k 0..31
  int cb = (4 + ldiv) ^ (lmod & 7);  // k 32..63

  int NT = kSplit >> 6;
  GSTAGE(0, 0);
  int cur = 0;
  for (int tt = 0; tt < NT; ++tt) {
    __syncthreads();  // drains vmcnt of loads issued one full compute-phase ago
    if (tt + 1 < NT) GSTAGE(cur ^ 1, (tt + 1) * 64);

    bf16x8 af[2][2], bfv[4][2];
#pragma unroll
    for (int i = 0; i < 2; ++i) {
      const __bf16* p = &As[cur][(wr * 32 + i * 16 + lmod) * 64];
      af[i][0] = *(const bf16x8*)(p + ca * 8);
      af[i][1] = *(const bf16x8*)(p + cb * 8);
    }
#pragma unroll
    for (int j = 0; j < 4; ++j) {
      const __bf16* p = &Bs[cur][(wc * 64 + j * 16 + lmod) * 64];
      bfv[j][0] = *(const bf16x8*)(p + ca * 8);
      bfv[j][1] = *(const bf16x8*)(p + cb * 8);
    }
    __builtin_amdgcn_s_setprio(1);
#pragma unroll
    for (int i = 0; i < 2; ++i)
#pragma unroll
      for (int j = 0; j < 4; ++j) {
        acc[i][j] = MFMA16(af[i][0], bfv[j][0], acc[i][j]);
        acc[i][j] = MFMA16(af[i][1], bfv[j][1], acc[i][j]);
      }
    __builtin_amdgcn_s_setprio(0);
    cur ^= 1;
  }

#pragma unroll
  for (int i = 0; i < 2; ++i) {
    int row0 = bm * 128 + wr * 32 + i * 16 + ldiv * 4;
#pragma unroll
    for (int j = 0; j < 4; ++j) {
      int col = bn * 128 + wc * 64 + j * 16 + lmod;
#pragma unroll
      for (int r = 0; r < 4; ++r) {
        if constexpr (ATOMIC) {
          atomicAdd((float*)&C[(size_t)(row0 + r) * N + col], acc[i][j][r]);
        } else {
          C[(size_t)(row0 + r) * N + col] = (OutT)acc[i][j][r];
        }
      }
    }
  }
}

// ---------------------------------------------------------------- RoPE + restructure
// Q pre-scaled by 0.125*log2e; Q path fully vectorized.
__global__ __launch_bounds__(256) void rope_restruct(__bf16* __restrict__ qkv,
                                                     const float* __restrict__ cosb,
                                                     const float* __restrict__ sinb,
                                                     __bf16* __restrict__ Kr,
                                                     __bf16* __restrict__ Vt) {
  int st = blockIdx.x * 64;
  int kvh = blockIdx.y;
  int t = threadIdx.x;
  __shared__ alignas(16) __bf16 vtile[64][72];
  const float csq = 0.125f * LOG2E;

  int r = t >> 2;
  int q4 = t & 3;
  int s = st + r;
  const float* cp = cosb + (size_t)s * 32;
  const float* sp = sinb + (size_t)s * 32;

  float cf[32], sf[32];
#pragma unroll
  for (int c = 0; c < 8; ++c) {
    f32x4v cv = *(const f32x4v*)(cp + c * 4);
    f32x4v sv = *(const f32x4v*)(sp + c * 4);
#pragma unroll
    for (int j = 0; j < 4; ++j) { cf[c * 4 + j] = cv[j]; sf[c * 4 + j] = sv[j]; }
  }

  {  // Q rope, vectorized: head h = kvh*4 + q4
    __bf16* p = qkv + (size_t)s * 3072 + (kvh * 4 + q4) * 64;
    bf16x8 q[8];
#pragma unroll
    for (int c = 0; c < 8; ++c) q[c] = *(const bf16x8*)(p + c * 8);
    float xf[32];
#pragma unroll
    for (int c = 0; c < 4; ++c)
#pragma unroll
      for (int j = 0; j < 8; ++j) xf[c * 8 + j] = (float)q[c][j];
    bf16x8 o[8];
#pragma unroll
    for (int d = 0; d < 16; ++d) {
      float o1 = (xf[d] * cf[d] - xf[d + 16] * sf[d]) * csq;
      float o2 = (xf[d + 16] * cf[d + 16] + xf[d] * sf[d + 16]) * csq;
      o[d >> 3][d & 7] = (__bf16)o1;
      o[(d + 16) >> 3][d & 7] = (__bf16)o2;
    }
#pragma unroll
    for (int c = 4; c < 8; ++c)
#pragma unroll
      for (int j = 0; j < 8; ++j) o[c][j] = (__bf16)((float)q[c][j] * csq);
#pragma unroll
    for (int c = 0; c < 8; ++c) *(bf16x8*)(p + c * 8) = o[c];
  }
  {  // K rope -> Kr
    const __bf16* p = qkv + (size_t)s * 3072 + 2048 + kvh * 64;
    __bf16* ko = Kr + ((size_t)kvh * 2048 + s) * 64;
    if (q4 == 0) {
      bf16x8 a0 = *(const bf16x8*)p, a1 = *(const bf16x8*)(p + 8);
      bf16x8 b0 = *(const bf16x8*)(p + 16), b1 = *(const bf16x8*)(p + 24);
      bf16x8 o0, o1;
#pragma unroll
      for (int j = 0; j < 8; ++j) {
        o0[j] = (__bf16)((float)a0[j] * cf[j] - (float)b0[j] * sf[j]);
        o1[j] = (__bf16)((float)a1[j] * cf[8 + j] - (float)b1[j] * sf[8 + j]);
      }
      *(bf16x8*)ko = o0;
      *(bf16x8*)(ko + 8) = o1;
    } else if (q4 == 1) {
      bf16x8 a0 = *(const bf16x8*)p, a1 = *(const bf16x8*)(p + 8);
      bf16x8 b0 = *(const bf16x8*)(p + 16), b1 = *(const bf16x8*)(p + 24);
      bf16x8 o0, o1;
#pragma unroll
      for (int j = 0; j < 8; ++j) {
        o0[j] = (__bf16)((float)b0[j] * cf[16 + j] + (float)a0[j] * sf[16 + j]);
        o1[j] = (__bf16)((float)b1[j] * cf[24 + j] + (float)a1[j] * sf[24 + j]);
      }
      *(bf16x8*)(ko + 16) = o0;
      *(bf16x8*)(ko + 24) = o1;
    } else if (q4 == 2) {
      *(bf16x8*)(ko + 32) = *(const bf16x8*)(p + 32);
      *(bf16x8*)(ko + 40) = *(const bf16x8*)(p + 40);
    } else {
      *(bf16x8*)(ko + 48) = *(const bf16x8*)(p + 48);
      *(bf16x8*)(ko + 56) = *(const bf16x8*)(p + 56);
    }
  }
  {  // V transpose -> Vt
    const __bf16* p = qkv + (size_t)s * 3072 + 2560 + kvh * 64 + q4 * 16;
    *(bf16x8*)&vtile[r][q4 * 16] = *(const bf16x8*)p;
    *(bf16x8*)&vtile[r][q4 * 16 + 8] = *(const bf16x8*)(p + 8);
  }
  __syncthreads();
  {
    int d = t >> 2;
    __bf16* vo = Vt + ((size_t)kvh * 64 + d) * 2048 + st + q4 * 16;
#pragma unroll
    for (int j = 0; j < 16; ++j) vo[j] = vtile[q4 * 16 + j][d];
  }
}

// ---------------------------------------------------------------- flash attention v9
// v6 core (QBLK=64, 4 waves x 16 q rows, KVBLK=64 dbuf, swapped QK^T, pi-permuted
// K staging, shift-free softmax) + CU-balanced qt map: grid (x=h, y=qi); CU's four
// blocks {qi, qi+8, qi+16, qi+24} map to qts {a, 15-a, 16+a, 31-a} (sum const).
__global__ __launch_bounds__(256) void attn_fwd(const __bf16* __restrict__ qkv,
                                                const __bf16* __restrict__ Kr,
                                                const __bf16* __restrict__ Vt,
                                                __bf16* __restrict__ O) {
  const int S = 2048, LDQ = 3072;
  int h = blockIdx.x;
  int a = blockIdx.y & 7, g = blockIdx.y >> 3;
  int qt = (g == 0) ? a : (g == 1) ? (15 - a) : (g == 2) ? (16 + a) : (31 - a);
  int kvh = h >> 2;
  int t = threadIdx.x;
  int lane = t & 63, w = t >> 6;  // 4 waves
  int lmod = lane & 15, ldiv = lane >> 4;

  __shared__ alignas(16) __bf16 KV[2][2][4096];  // [buf][K/V][row*64+col], 32KB

  int R0 = qt * 64 + w * 16;  // this wave's 16 q rows

  const __bf16* qp = qkv + (size_t)(R0 + lmod) * LDQ + h * 64 + ldiv * 8;
  bf16x8 qf0 = *(const bf16x8*)qp;
  bf16x8 qf1 = *(const bf16x8*)(qp + 32);

  f32x4 acc[4] = {};
  f32x4 lacc = {};
  int nkt = qt + 1;

  const __bf16* Kg = Kr + (size_t)kvh * S * 64;
  const __bf16* Vg = Vt + (size_t)kvh * 64 * S;
  int srow8 = lane >> 3;          // row-within-8 of chunk
  int schk = (lane & 7) ^ srow8;  // swizzled in-row 16B-chunk index

#define STAGE(buf, ks)                                                            \
  {                                                                               \
    __bf16* kb = &KV[buf][0][0];                                                  \
    __bf16* vb = &KV[buf][1][0];                                                  \
    _Pragma("unroll") for (int c = 0; c < 2; ++c) {                               \
      int c1kb = w * 2 + c;                                                       \
      int rr = c1kb * 8 + srow8;                                                  \
      int rrg = (rr & 0x23) | ((rr & 0x0C) << 1) | ((rr & 0x10) >> 2);            \
      gload_lds16(Kg + (size_t)((ks) + rrg) * 64 + schk * 8, kb + c1kb * 512);    \
      gload_lds16(Vg + (size_t)rr * S + (ks) + schk * 8, vb + c1kb * 512);        \
    }                                                                             \
  }

  STAGE(0, 0);

  int r7 = lmod & 7;
  int ca = ldiv ^ r7;        // swizzled chunk, k-slots 0..31 half
  int cb = (4 + ldiv) ^ r7;  // k-slots 32..63 half

  int cur = 0;
  for (int kt = 0; kt < nkt; ++kt) {
    int ks = kt * 64;
    __syncthreads();  // drains own gload vmcnt (issued one compute-phase ago)
    if (kt + 1 < nkt) STAGE(cur ^ 1, ks + 64);
    const __bf16* Ksb = &KV[cur][0][0];
    const __bf16* Vsb = &KV[cur][1][0];

    // ---- QK^T (swapped): reg (t16,r) of lane (q=lmod,d=ldiv) holds score for
    // global k = ks + 32*(t16>>1) + 4*(t16&1) + 8*d + r (pi-permuted staging).
    f32x4 st[4] = {};
    __builtin_amdgcn_s_setprio(1);
#pragma unroll
    for (int t16 = 0; t16 < 4; ++t16) {
      int row = t16 * 16 + lmod;
      bf16x8 kf0 = *(const bf16x8*)(Ksb + row * 64 + ca * 8);
      bf16x8 kf1 = *(const bf16x8*)(Ksb + row * 64 + cb * 8);
      st[t16] = MFMA16(kf0, qf0, st[t16]);
      st[t16] = MFMA16(kf1, qf1, st[t16]);
    }
    __builtin_amdgcn_s_setprio(0);

    if (kt == nkt - 1) {  // diagonal tile: causal mask (permuted k formula)
      int qq = R0 + lmod;
#pragma unroll
      for (int t16 = 0; t16 < 4; ++t16) {
        int kk = ks + (t16 >> 1) * 32 + (t16 & 1) * 4 + ldiv * 8;
#pragma unroll
        for (int r = 0; r < 4; ++r)
          st[t16][r] = (kk + r) <= qq ? st[t16][r] : -1e30f;
      }
    }

    // V fragments
    bf16x8 vf[8];
#pragma unroll
    for (int g2 = 0; g2 < 4; ++g2) {
      int row = g2 * 16 + lmod;
      vf[g2] = *(const bf16x8*)(Vsb + row * 64 + ca * 8);
      vf[4 + g2] = *(const bf16x8*)(Vsb + row * 64 + cb * 8);
    }

    // ---- shift-free softmax: p = exp2(st); per-lane partial sums
#pragma unroll
    for (int t16 = 0; t16 < 4; ++t16)
#pragma unroll
      for (int r = 0; r < 4; ++r) {
        float pv = __builtin_amdgcn_exp2f(st[t16][r]);
        st[t16][r] = pv;
        lacc[r] += pv;
      }

    // pack P: registers are already in PV A-fragment order (pi staging)
    u32x4 av0, av1;
    av0[0] = pk2(st[0][0], st[0][1]);
    av0[1] = pk2(st[0][2], st[0][3]);
    av0[2] = pk2(st[1][0], st[1][1]);
    av0[3] = pk2(st[1][2], st[1][3]);
    av1[0] = pk2(st[2][0], st[2][1]);
    av1[1] = pk2(st[2][2], st[2][3]);
    av1[2] = pk2(st[3][0], st[3][1]);
    av1[3] = pk2(st[3][2], st[3][3]);
    bf16x8 pa0 = __builtin_bit_cast(bf16x8, av0);
    bf16x8 pa1 = __builtin_bit_cast(bf16x8, av1);

    __builtin_amdgcn_s_setprio(1);
#pragma unroll
    for (int g2 = 0; g2 < 4; ++g2) {
      acc[g2] = MFMA16(pa0, vf[g2], acc[g2]);
      acc[g2] = MFMA16(pa1, vf[4 + g2], acc[g2]);
    }
    __builtin_amdgcn_s_setprio(0);
    cur ^= 1;
  }

  // epilogue: reduce l across lanes once, then normalize
  {
    float lsum = lacc[0] + lacc[1] + lacc[2] + lacc[3];
    lsum += __shfl_xor(lsum, 16);
    lsum += __shfl_xor(lsum, 32);
    float linv[4];
#pragma unroll
    for (int r = 0; r < 4; ++r) {
      float lq = __shfl(lsum, ldiv * 4 + r);
      linv[r] = 1.0f / lq;
    }
#pragma unroll
    for (int g2 = 0; g2 < 4; ++g2)
#pragma unroll
      for (int r = 0; r < 4; ++r)
        O[(size_t)(R0 + ldiv * 4 + r) * 2048 + h * 64 + g2 * 16 + lmod] =
            (__bf16)(acc[g2][r] * linv[r]);
  }
}

// ---------------------------------------------------------------- launch
extern "C" void kernel_launch(void* const* d_in, const int* in_sizes, int n_in,
                              void* d_out, int out_size, void* d_ws, size_t ws_size,
                              hipStream_t stream) {
  const float* x = (const float*)d_in[0];
  const float* cosb = (const float*)d_in[1];
  const float* sinb = (const float*)d_in[2];
  const float* wqkv = (const float*)d_in[3];
  const float* wo = (const float*)d_in[4];
  float* out = (float*)d_out;

  char* ws = (char*)d_ws;
  __bf16* xb    = (__bf16*)(ws + 0);
  __bf16* wqkvT = (__bf16*)(ws + 8388608);
  __bf16* woT   = (__bf16*)(ws + 20971520);
  __bf16* qkvb  = (__bf16*)(ws + 29360128);
  __bf16* Krb   = (__bf16*)(ws + 41943040);
  __bf16* Vtb   = (__bf16*)(ws + 44040192);
  __bf16* attnb = (__bf16*)(ws + 46137344);

  // zero d_out for split-K atomic accumulation (graph-capturable)
  hipMemsetAsync(d_out, 0, (size_t)out_size * sizeof(float), stream);

  prep<<<6656, 256, 0, stream>>>(x, xb, wqkv, wqkvT, wo, woT);
  gemm8w<__bf16, false><<<dim3(24, 16), 512, 0, stream>>>(xb, wqkvT, qkvb,
                                                          2048, 3072, 2048, 2048);
  rope_restruct<<<dim3(32, 8), 256, 0, stream>>>(qkvb, cosb, sinb, Krb, Vtb);
  attn_fwd<<<dim3(32, 32), 256, 0, stream>>>(qkvb, Krb, Vtb, attnb);
  gemm8w<float, true><<<dim3(16, 16, 2), 512, 0, stream>>>(attnb, woT, out,
                                                           2048, 2048, 2048, 1024);
}

// Round 12
// 130.210 us; speedup vs baseline: 1.0692x; 1.0692x over previous
//
#include <hip/hip_runtime.h>
#include <hip/hip_bf16.h>
#include <stdint.h>

typedef float f32x4 __attribute__((ext_vector_type(4)));
typedef float f32x4v __attribute__((ext_vector_type(4)));
typedef __bf16 bf16x8 __attribute__((ext_vector_type(8)));
typedef __bf16 bf16x4 __attribute__((ext_vector_type(4)));
typedef __bf16 bf16x2 __attribute__((ext_vector_type(2)));
typedef unsigned int u32x4 __attribute__((ext_vector_type(4)));

#define LOG2E 1.44269504088896340736f
#define MFMA16(a, b, c) __builtin_amdgcn_mfma_f32_16x16x32_bf16((a), (b), (c), 0, 0, 0)

static __device__ __forceinline__ void gload_lds16(const void* g, void* l) {
  __builtin_amdgcn_global_load_lds(
      (const __attribute__((address_space(1))) unsigned int*)g,
      (__attribute__((address_space(3))) unsigned int*)l, 16, 0, 0);
}

static __device__ __forceinline__ uint32_t pk2(float lo, float hi) {
  bf16x2 v;
  v[0] = (__bf16)lo;
  v[1] = (__bf16)hi;
  return __builtin_bit_cast(uint32_t, v);
}

// ---------------------------------------------------------------- prep: cvt + both transposes
__global__ __launch_bounds__(256) void prep(const float* __restrict__ x,
                                            __bf16* __restrict__ xb,
                                            const float* __restrict__ wqkv,
                                            __bf16* __restrict__ wqkvT,
                                            const float* __restrict__ wo,
                                            __bf16* __restrict__ woT) {
  __shared__ float tile[64][65];
  int b = blockIdx.x;
  int t = threadIdx.x;
  if (b < 4096) {
    int i = b * 256 + t;
    f32x4v v = *(const f32x4v*)(x + (size_t)i * 4);
    bf16x4 o;
    o[0] = (__bf16)v[0]; o[1] = (__bf16)v[1]; o[2] = (__bf16)v[2]; o[3] = (__bf16)v[3];
    *(bf16x4*)(xb + (size_t)i * 4) = o;
    return;
  }
  const float* in;
  __bf16* out;
  int R, C, bx, by;
  if (b < 5632) {
    int bb = b - 4096;
    in = wqkv; out = wqkvT; R = 2048; C = 3072; bx = bb % 48; by = bb / 48;
  } else {
    int bb = b - 5632;
    in = wo; out = woT; R = 2048; C = 2048; bx = bb & 31; by = bb >> 5;
  }
  int tr = by * 64, tc = bx * 64;
  int r0 = t >> 4;
  int c4 = (t & 15) * 4;
#pragma unroll
  for (int i = 0; i < 4; ++i) {
    int r = r0 + i * 16;
    f32x4v v = *(const f32x4v*)(in + (size_t)(tr + r) * C + tc + c4);
    tile[r][c4 + 0] = v[0]; tile[r][c4 + 1] = v[1];
    tile[r][c4 + 2] = v[2]; tile[r][c4 + 3] = v[3];
  }
  __syncthreads();
#pragma unroll
  for (int i = 0; i < 4; ++i) {
    int r = r0 + i * 16;
    __bf16* o = out + (size_t)(tc + r) * R + tr + c4;
    bf16x4 ov;
    ov[0] = (__bf16)tile[c4 + 0][r]; ov[1] = (__bf16)tile[c4 + 1][r];
    ov[2] = (__bf16)tile[c4 + 2][r]; ov[3] = (__bf16)tile[c4 + 3][r];
    *(bf16x4*)o = ov;
  }
}

// ---------------------------------------------------------------- GEMM: 8-wave (512t),
// 128x128 tile, BK=64, 1-barrier dbuf, XOR-swizzled LDS, XCD swizzle (gx%8==0).
template <typename OutT>
__global__ __launch_bounds__(512) void gemm8w(const __bf16* __restrict__ A,
                                              const __bf16* __restrict__ BT,
                                              OutT* __restrict__ C,
                                              int M, int N, int K) {
  __shared__ alignas(16) __bf16 As[2][128 * 64];
  __shared__ alignas(16) __bf16 Bs[2][128 * 64];
  int gx = gridDim.x;
  int l = blockIdx.y * gx + blockIdx.x;
  int cpx = gx >> 3;
  int xcd = l & 7, rr0 = l >> 3;
  int bn = xcd * cpx + rr0 % cpx;
  int bm = rr0 / cpx;
  int t = threadIdx.x;
  int lane = t & 63, w = t >> 6;  // 8 waves
  int lmod = lane & 15, ldiv = lane >> 4;
  int wr = w >> 1, wc = w & 1;

  f32x4 acc[2][4] = {};

  int sr8 = lane >> 3;
  int sk = (lane & 7) ^ sr8;  // pre-swizzled global source chunk
  const __bf16* gaB[2];
  const __bf16* gbB[2];
#pragma unroll
  for (int c = 0; c < 2; ++c) {
    int rr = (2 * w + c) * 8 + sr8;
    gaB[c] = A + (size_t)(bm * 128 + rr) * K + sk * 8;
    gbB[c] = BT + (size_t)(bn * 128 + rr) * K + sk * 8;
  }

#define GSTAGE(buf, k0)                                                \
  {                                                                    \
    _Pragma("unroll") for (int c = 0; c < 2; ++c) {                    \
      gload_lds16(gaB[c] + (k0), &As[buf][(2 * w + c) * 512]);         \
      gload_lds16(gbB[c] + (k0), &Bs[buf][(2 * w + c) * 512]);         \
    }                                                                  \
  }

  int ca = ldiv ^ (lmod & 7);        // swizzled chunk, k 0..31
  int cb = (4 + ldiv) ^ (lmod & 7);  // k 32..63

  int NT = K >> 6;
  GSTAGE(0, 0);
  int cur = 0;
  for (int tt = 0; tt < NT; ++tt) {
    __syncthreads();  // drains vmcnt of loads issued one full compute-phase ago
    if (tt + 1 < NT) GSTAGE(cur ^ 1, (tt + 1) * 64);

    bf16x8 af[2][2], bfv[4][2];
#pragma unroll
    for (int i = 0; i < 2; ++i) {
      const __bf16* p = &As[cur][(wr * 32 + i * 16 + lmod) * 64];
      af[i][0] = *(const bf16x8*)(p + ca * 8);
      af[i][1] = *(const bf16x8*)(p + cb * 8);
    }
#pragma unroll
    for (int j = 0; j < 4; ++j) {
      const __bf16* p = &Bs[cur][(wc * 64 + j * 16 + lmod) * 64];
      bfv[j][0] = *(const bf16x8*)(p + ca * 8);
      bfv[j][1] = *(const bf16x8*)(p + cb * 8);
    }
    __builtin_amdgcn_s_setprio(1);
#pragma unroll
    for (int i = 0; i < 2; ++i)
#pragma unroll
      for (int j = 0; j < 4; ++j) {
        acc[i][j] = MFMA16(af[i][0], bfv[j][0], acc[i][j]);
        acc[i][j] = MFMA16(af[i][1], bfv[j][1], acc[i][j]);
      }
    __builtin_amdgcn_s_setprio(0);
    cur ^= 1;
  }

#pragma unroll
  for (int i = 0; i < 2; ++i) {
    int row0 = bm * 128 + wr * 32 + i * 16 + ldiv * 4;
#pragma unroll
    for (int j = 0; j < 4; ++j) {
      int col = bn * 128 + wc * 64 + j * 16 + lmod;
#pragma unroll
      for (int r = 0; r < 4; ++r)
        C[(size_t)(row0 + r) * N + col] = (OutT)acc[i][j][r];
    }
  }
}

// ---------------------------------------------------------------- RoPE + restructure
__global__ __launch_bounds__(256) void rope_restruct(__bf16* __restrict__ qkv,
                                                     const float* __restrict__ cosb,
                                                     const float* __restrict__ sinb,
                                                     __bf16* __restrict__ Kr,
                                                     __bf16* __restrict__ Vt) {
  int st = blockIdx.x * 64;
  int kvh = blockIdx.y;
  int t = threadIdx.x;
  __shared__ alignas(16) __bf16 vtile[64][72];
  const float csq = 0.125f * LOG2E;

  int r = t >> 2;
  int q4 = t & 3;
  int s = st + r;
  const float* cp = cosb + (size_t)s * 32;
  const float* sp = sinb + (size_t)s * 32;

  float cf[32], sf[32];
#pragma unroll
  for (int c = 0; c < 8; ++c) {
    f32x4v cv = *(const f32x4v*)(cp + c * 4);
    f32x4v sv = *(const f32x4v*)(sp + c * 4);
#pragma unroll
    for (int j = 0; j < 4; ++j) { cf[c * 4 + j] = cv[j]; sf[c * 4 + j] = sv[j]; }
  }

  {  // Q rope, vectorized: head h = kvh*4 + q4
    __bf16* p = qkv + (size_t)s * 3072 + (kvh * 4 + q4) * 64;
    bf16x8 q[8];
#pragma unroll
    for (int c = 0; c < 8; ++c) q[c] = *(const bf16x8*)(p + c * 8);
    float xf[32];
#pragma unroll
    for (int c = 0; c < 4; ++c)
#pragma unroll
      for (int j = 0; j < 8; ++j) xf[c * 8 + j] = (float)q[c][j];
    bf16x8 o[8];
#pragma unroll
    for (int d = 0; d < 16; ++d) {
      float o1 = (xf[d] * cf[d] - xf[d + 16] * sf[d]) * csq;
      float o2 = (xf[d + 16] * cf[d + 16] + xf[d] * sf[d + 16]) * csq;
      o[d >> 3][d & 7] = (__bf16)o1;
      o[(d + 16) >> 3][d & 7] = (__bf16)o2;
    }
#pragma unroll
    for (int c = 4; c < 8; ++c)
#pragma unroll
      for (int j = 0; j < 8; ++j) o[c][j] = (__bf16)((float)q[c][j] * csq);
#pragma unroll
    for (int c = 0; c < 8; ++c) *(bf16x8*)(p + c * 8) = o[c];
  }
  {  // K rope -> Kr
    const __bf16* p = qkv + (size_t)s * 3072 + 2048 + kvh * 64;
    __bf16* ko = Kr + ((size_t)kvh * 2048 + s) * 64;
    if (q4 == 0) {
      bf16x8 a0 = *(const bf16x8*)p, a1 = *(const bf16x8*)(p + 8);
      bf16x8 b0 = *(const bf16x8*)(p + 16), b1 = *(const bf16x8*)(p + 24);
      bf16x8 o0, o1;
#pragma unroll
      for (int j = 0; j < 8; ++j) {
        o0[j] = (__bf16)((float)a0[j] * cf[j] - (float)b0[j] * sf[j]);
        o1[j] = (__bf16)((float)a1[j] * cf[8 + j] - (float)b1[j] * sf[8 + j]);
      }
      *(bf16x8*)ko = o0;
      *(bf16x8*)(ko + 8) = o1;
    } else if (q4 == 1) {
      bf16x8 a0 = *(const bf16x8*)p, a1 = *(const bf16x8*)(p + 8);
      bf16x8 b0 = *(const bf16x8*)(p + 16), b1 = *(const bf16x8*)(p + 24);
      bf16x8 o0, o1;
#pragma unroll
      for (int j = 0; j < 8; ++j) {
        o0[j] = (__bf16)((float)b0[j] * cf[16 + j] + (float)a0[j] * sf[16 + j]);
        o1[j] = (__bf16)((float)b1[j] * cf[24 + j] + (float)a1[j] * sf[24 + j]);
      }
      *(bf16x8*)(ko + 16) = o0;
      *(bf16x8*)(ko + 24) = o1;
    } else if (q4 == 2) {
      *(bf16x8*)(ko + 32) = *(const bf16x8*)(p + 32);
      *(bf16x8*)(ko + 40) = *(const bf16x8*)(p + 40);
    } else {
      *(bf16x8*)(ko + 48) = *(const bf16x8*)(p + 48);
      *(bf16x8*)(ko + 56) = *(const bf16x8*)(p + 56);
    }
  }
  {  // V transpose -> Vt
    const __bf16* p = qkv + (size_t)s * 3072 + 2560 + kvh * 64 + q4 * 16;
    *(bf16x8*)&vtile[r][q4 * 16] = *(const bf16x8*)p;
    *(bf16x8*)&vtile[r][q4 * 16 + 8] = *(const bf16x8*)(p + 8);
  }
  __syncthreads();
  {
    int d = t >> 2;
    __bf16* vo = Vt + ((size_t)kvh * 64 + d) * 2048 + st + q4 * 16;
#pragma unroll
    for (int j = 0; j < 16; ++j) vo[j] = vtile[q4 * 16 + j][d];
  }
}

// ---------------------------------------------------------------- flash attention v10
// QBLK=128 (4 waves x 32 q rows = 2 q-groups), KVBLK=64 dbuf, swapped QK^T,
// pi-permuted K staging, shift-free softmax, CU-balanced qt map:
// grid (x=h 32, y=qi 16); CU pair {qi, qi+8} -> qts {a, 15-a} (work sum const).
__global__ __launch_bounds__(256) void attn_fwd(const __bf16* __restrict__ qkv,
                                                const __bf16* __restrict__ Kr,
                                                const __bf16* __restrict__ Vt,
                                                __bf16* __restrict__ O) {
  const int S = 2048, LDQ = 3072;
  int h = blockIdx.x;
  int qi = blockIdx.y;
  int qt = (qi < 8) ? qi : (23 - qi);
  int kvh = h >> 2;
  int t = threadIdx.x;
  int lane = t & 63, w = t >> 6;  // 4 waves
  int lmod = lane & 15, ldiv = lane >> 4;

  __shared__ alignas(16) __bf16 KV[2][2][4096];  // [buf][K/V][row*64+col], 32KB

  int R0 = qt * 128 + w * 32;  // this wave's 32 q rows

  bf16x8 qf[2][2];
#pragma unroll
  for (int qg = 0; qg < 2; ++qg) {
    const __bf16* qp = qkv + (size_t)(R0 + qg * 16 + lmod) * LDQ + h * 64 + ldiv * 8;
    qf[qg][0] = *(const bf16x8*)qp;
    qf[qg][1] = *(const bf16x8*)(qp + 32);
  }

  f32x4 acc[2][4] = {};
  f32x4 lacc[2] = {};
  int nkt = 2 * qt + 2;
  int ktd = 2 * qt + (w >> 1);  // waves 0,1 skip the final tile's compute

  const __bf16* Kg = Kr + (size_t)kvh * S * 64;
  const __bf16* Vg = Vt + (size_t)kvh * 64 * S;
  int srow8 = lane >> 3;          // row-within-8 of chunk
  int schk = (lane & 7) ^ srow8;  // swizzled in-row 16B-chunk index

#define STAGE(buf, ks)                                                            \
  {                                                                               \
    __bf16* kb = &KV[buf][0][0];                                                  \
    __bf16* vb = &KV[buf][1][0];                                                  \
    _Pragma("unroll") for (int c = 0; c < 2; ++c) {                               \
      int c1kb = w * 2 + c;                                                       \
      int rr = c1kb * 8 + srow8;                                                  \
      int rrg = (rr & 0x23) | ((rr & 0x0C) << 1) | ((rr & 0x10) >> 2);            \
      gload_lds16(Kg + (size_t)((ks) + rrg) * 64 + schk * 8, kb + c1kb * 512);    \
      gload_lds16(Vg + (size_t)rr * S + (ks) + schk * 8, vb + c1kb * 512);        \
    }                                                                             \
  }

  STAGE(0, 0);

  int r7 = lmod & 7;
  int ca = ldiv ^ r7;        // swizzled chunk, k-slots 0..31 half
  int cb = (4 + ldiv) ^ r7;  // k-slots 32..63 half

  int cur = 0;
  for (int kt = 0; kt < nkt; ++kt) {
    int ks = kt * 64;
    __syncthreads();  // drains own gload vmcnt (issued one compute-phase ago)
    if (kt + 1 < nkt) STAGE(cur ^ 1, ks + 64);
    if (kt <= ktd) {
      const __bf16* Ksb = &KV[cur][0][0];
      const __bf16* Vsb = &KV[cur][1][0];

      // ---- QK^T (swapped): reg (t16,r) of lane (q,d) holds score for
      // global k = ks + 32*(t16>>1) + 4*(t16&1) + 8*d + r (pi staging).
      f32x4 st[2][4] = {};
      __builtin_amdgcn_s_setprio(1);
#pragma unroll
      for (int t16 = 0; t16 < 4; ++t16) {
        int row = t16 * 16 + lmod;
        bf16x8 kf0 = *(const bf16x8*)(Ksb + row * 64 + ca * 8);
        bf16x8 kf1 = *(const bf16x8*)(Ksb + row * 64 + cb * 8);
        st[0][t16] = MFMA16(kf0, qf[0][0], st[0][t16]);
        st[0][t16] = MFMA16(kf1, qf[0][1], st[0][t16]);
        st[1][t16] = MFMA16(kf0, qf[1][0], st[1][t16]);
        st[1][t16] = MFMA16(kf1, qf[1][1], st[1][t16]);
      }
      __builtin_amdgcn_s_setprio(0);

      if (kt == ktd) {  // diagonal tile: causal mask (permuted k formula)
#pragma unroll
        for (int qg = 0; qg < 2; ++qg) {
          int qq = R0 + qg * 16 + lmod;
#pragma unroll
          for (int t16 = 0; t16 < 4; ++t16) {
            int kk = ks + (t16 >> 1) * 32 + (t16 & 1) * 4 + ldiv * 8;
#pragma unroll
            for (int r = 0; r < 4; ++r)
              st[qg][t16][r] = (kk + r) <= qq ? st[qg][t16][r] : -1e30f;
          }
        }
      }

      // V fragments (shared by both q-groups)
      bf16x8 vf[8];
#pragma unroll
      for (int g2 = 0; g2 < 4; ++g2) {
        int row = g2 * 16 + lmod;
        vf[g2] = *(const bf16x8*)(Vsb + row * 64 + ca * 8);
        vf[4 + g2] = *(const bf16x8*)(Vsb + row * 64 + cb * 8);
      }

#pragma unroll
      for (int qg = 0; qg < 2; ++qg) {
        // shift-free softmax: p = exp2(st); per-lane partial sums
#pragma unroll
        for (int t16 = 0; t16 < 4; ++t16)
#pragma unroll
          for (int r = 0; r < 4; ++r) {
            float pv = __builtin_amdgcn_exp2f(st[qg][t16][r]);
            st[qg][t16][r] = pv;
            lacc[qg][r] += pv;
          }

        // pack P: registers already in PV A-fragment order (pi staging)
        u32x4 av0, av1;
        av0[0] = pk2(st[qg][0][0], st[qg][0][1]);
        av0[1] = pk2(st[qg][0][2], st[qg][0][3]);
        av0[2] = pk2(st[qg][1][0], st[qg][1][1]);
        av0[3] = pk2(st[qg][1][2], st[qg][1][3]);
        av1[0] = pk2(st[qg][2][0], st[qg][2][1]);
        av1[1] = pk2(st[qg][2][2], st[qg][2][3]);
        av1[2] = pk2(st[qg][3][0], st[qg][3][1]);
        av1[3] = pk2(st[qg][3][2], st[qg][3][3]);
        bf16x8 pa0 = __builtin_bit_cast(bf16x8, av0);
        bf16x8 pa1 = __builtin_bit_cast(bf16x8, av1);

        __builtin_amdgcn_s_setprio(1);
#pragma unroll
        for (int g2 = 0; g2 < 4; ++g2) {
          acc[qg][g2] = MFMA16(pa0, vf[g2], acc[qg][g2]);
          acc[qg][g2] = MFMA16(pa1, vf[4 + g2], acc[qg][g2]);
        }
        __builtin_amdgcn_s_setprio(0);
      }
    }
    cur ^= 1;
  }

  // epilogue: reduce l across lanes once per q-group, then normalize
#pragma unroll
  for (int qg = 0; qg < 2; ++qg) {
    float lsum = lacc[qg][0] + lacc[qg][1] + lacc[qg][2] + lacc[qg][3];
    lsum += __shfl_xor(lsum, 16);
    lsum += __shfl_xor(lsum, 32);
    float linv[4];
#pragma unroll
    for (int r = 0; r < 4; ++r) {
      float lq = __shfl(lsum, ldiv * 4 + r);
      linv[r] = 1.0f / lq;
    }
#pragma unroll
    for (int g2 = 0; g2 < 4; ++g2)
#pragma unroll
      for (int r = 0; r < 4; ++r)
        O[(size_t)(R0 + qg * 16 + ldiv * 4 + r) * 2048 + h * 64 + g2 * 16 + lmod] =
            (__bf16)(acc[qg][g2][r] * linv[r]);
  }
}

// ---------------------------------------------------------------- launch
extern "C" void kernel_launch(void* const* d_in, const int* in_sizes, int n_in,
                              void* d_out, int out_size, void* d_ws, size_t ws_size,
                              hipStream_t stream) {
  const float* x = (const float*)d_in[0];
  const float* cosb = (const float*)d_in[1];
  const float* sinb = (const float*)d_in[2];
  const float* wqkv = (const float*)d_in[3];
  const float* wo = (const float*)d_in[4];
  float* out = (float*)d_out;

  char* ws = (char*)d_ws;
  __bf16* xb    = (__bf16*)(ws + 0);
  __bf16* wqkvT = (__bf16*)(ws + 8388608);
  __bf16* woT   = (__bf16*)(ws + 20971520);
  __bf16* qkvb  = (__bf16*)(ws + 29360128);
  __bf16* Krb   = (__bf16*)(ws + 41943040);
  __bf16* Vtb   = (__bf16*)(ws + 44040192);
  __bf16* attnb = (__bf16*)(ws + 46137344);

  prep<<<6656, 256, 0, stream>>>(x, xb, wqkv, wqkvT, wo, woT);
  gemm8w<__bf16><<<dim3(24, 16), 512, 0, stream>>>(xb, wqkvT, qkvb, 2048, 3072, 2048);
  rope_restruct<<<dim3(32, 8), 256, 0, stream>>>(qkvb, cosb, sinb, Krb, Vtb);
  attn_fwd<<<dim3(32, 16), 256, 0, stream>>>(qkvb, Krb, Vtb, attnb);
  gemm8w<float><<<dim3(16, 16), 512, 0, stream>>>(attnb, woT, out, 2048, 2048, 2048);
}

// Round 13
// 116.415 us; speedup vs baseline: 1.1959x; 1.1185x over previous
//
#include <hip/hip_runtime.h>
#include <hip/hip_bf16.h>
#include <stdint.h>

typedef float f32x4 __attribute__((ext_vector_type(4)));
typedef float f32x4v __attribute__((ext_vector_type(4)));
typedef __bf16 bf16x8 __attribute__((ext_vector_type(8)));
typedef __bf16 bf16x4 __attribute__((ext_vector_type(4)));
typedef __bf16 bf16x2 __attribute__((ext_vector_type(2)));
typedef unsigned int u32x4 __attribute__((ext_vector_type(4)));

#define LOG2E 1.44269504088896340736f
#define MFMA16(a, b, c) __builtin_amdgcn_mfma_f32_16x16x32_bf16((a), (b), (c), 0, 0, 0)

static __device__ __forceinline__ void gload_lds16(const void* g, void* l) {
  __builtin_amdgcn_global_load_lds(
      (const __attribute__((address_space(1))) unsigned int*)g,
      (__attribute__((address_space(3))) unsigned int*)l, 16, 0, 0);
}

static __device__ __forceinline__ uint32_t pk2(float lo, float hi) {
  bf16x2 v;
  v[0] = (__bf16)lo;
  v[1] = (__bf16)hi;
  return __builtin_bit_cast(uint32_t, v);
}

// ---------------------------------------------------------------- prep: cvt + both transposes
__global__ __launch_bounds__(256) void prep(const float* __restrict__ x,
                                            __bf16* __restrict__ xb,
                                            const float* __restrict__ wqkv,
                                            __bf16* __restrict__ wqkvT,
                                            const float* __restrict__ wo,
                                            __bf16* __restrict__ woT) {
  __shared__ float tile[64][65];
  int b = blockIdx.x;
  int t = threadIdx.x;
  if (b < 4096) {
    int i = b * 256 + t;
    f32x4v v = *(const f32x4v*)(x + (size_t)i * 4);
    bf16x4 o;
    o[0] = (__bf16)v[0]; o[1] = (__bf16)v[1]; o[2] = (__bf16)v[2]; o[3] = (__bf16)v[3];
    *(bf16x4*)(xb + (size_t)i * 4) = o;
    return;
  }
  const float* in;
  __bf16* out;
  int R, C, bx, by;
  if (b < 5632) {
    int bb = b - 4096;
    in = wqkv; out = wqkvT; R = 2048; C = 3072; bx = bb % 48; by = bb / 48;
  } else {
    int bb = b - 5632;
    in = wo; out = woT; R = 2048; C = 2048; bx = bb & 31; by = bb >> 5;
  }
  int tr = by * 64, tc = bx * 64;
  int r0 = t >> 4;
  int c4 = (t & 15) * 4;
#pragma unroll
  for (int i = 0; i < 4; ++i) {
    int r = r0 + i * 16;
    f32x4v v = *(const f32x4v*)(in + (size_t)(tr + r) * C + tc + c4);
    tile[r][c4 + 0] = v[0]; tile[r][c4 + 1] = v[1];
    tile[r][c4 + 2] = v[2]; tile[r][c4 + 3] = v[3];
  }
  __syncthreads();
#pragma unroll
  for (int i = 0; i < 4; ++i) {
    int r = r0 + i * 16;
    __bf16* o = out + (size_t)(tc + r) * R + tr + c4;
    bf16x4 ov;
    ov[0] = (__bf16)tile[c4 + 0][r]; ov[1] = (__bf16)tile[c4 + 1][r];
    ov[2] = (__bf16)tile[c4 + 2][r]; ov[3] = (__bf16)tile[c4 + 3][r];
    *(bf16x4*)o = ov;
  }
}

// ---------------------------------------------------------------- GEMM A: 8-wave (512t),
// 128x128 tile, BK=64, 1-barrier dbuf, XOR-swizzled LDS, XCD swizzle (gx%8==0).
template <typename OutT>
__global__ __launch_bounds__(512) void gemm8w(const __bf16* __restrict__ A,
                                              const __bf16* __restrict__ BT,
                                              OutT* __restrict__ C,
                                              int M, int N, int K) {
  __shared__ alignas(16) __bf16 As[2][128 * 64];
  __shared__ alignas(16) __bf16 Bs[2][128 * 64];
  int gx = gridDim.x;
  int l = blockIdx.y * gx + blockIdx.x;
  int cpx = gx >> 3;
  int xcd = l & 7, rr0 = l >> 3;
  int bn = xcd * cpx + rr0 % cpx;
  int bm = rr0 / cpx;
  int t = threadIdx.x;
  int lane = t & 63, w = t >> 6;  // 8 waves
  int lmod = lane & 15, ldiv = lane >> 4;
  int wr = w >> 1, wc = w & 1;

  f32x4 acc[2][4] = {};

  int sr8 = lane >> 3;
  int sk = (lane & 7) ^ sr8;  // pre-swizzled global source chunk
  const __bf16* gaB[2];
  const __bf16* gbB[2];
#pragma unroll
  for (int c = 0; c < 2; ++c) {
    int rr = (2 * w + c) * 8 + sr8;
    gaB[c] = A + (size_t)(bm * 128 + rr) * K + sk * 8;
    gbB[c] = BT + (size_t)(bn * 128 + rr) * K + sk * 8;
  }

#define GSTAGE(buf, k0)                                                \
  {                                                                    \
    _Pragma("unroll") for (int c = 0; c < 2; ++c) {                    \
      gload_lds16(gaB[c] + (k0), &As[buf][(2 * w + c) * 512]);         \
      gload_lds16(gbB[c] + (k0), &Bs[buf][(2 * w + c) * 512]);         \
    }                                                                  \
  }

  int ca = ldiv ^ (lmod & 7);        // swizzled chunk, k 0..31
  int cb = (4 + ldiv) ^ (lmod & 7);  // k 32..63

  int NT = K >> 6;
  GSTAGE(0, 0);
  int cur = 0;
  for (int tt = 0; tt < NT; ++tt) {
    __syncthreads();
    if (tt + 1 < NT) GSTAGE(cur ^ 1, (tt + 1) * 64);

    bf16x8 af[2][2], bfv[4][2];
#pragma unroll
    for (int i = 0; i < 2; ++i) {
      const __bf16* p = &As[cur][(wr * 32 + i * 16 + lmod) * 64];
      af[i][0] = *(const bf16x8*)(p + ca * 8);
      af[i][1] = *(const bf16x8*)(p + cb * 8);
    }
#pragma unroll
    for (int j = 0; j < 4; ++j) {
      const __bf16* p = &Bs[cur][(wc * 64 + j * 16 + lmod) * 64];
      bfv[j][0] = *(const bf16x8*)(p + ca * 8);
      bfv[j][1] = *(const bf16x8*)(p + cb * 8);
    }
    __builtin_amdgcn_s_setprio(1);
#pragma unroll
    for (int i = 0; i < 2; ++i)
#pragma unroll
      for (int j = 0; j < 4; ++j) {
        acc[i][j] = MFMA16(af[i][0], bfv[j][0], acc[i][j]);
        acc[i][j] = MFMA16(af[i][1], bfv[j][1], acc[i][j]);
      }
    __builtin_amdgcn_s_setprio(0);
    cur ^= 1;
  }

#pragma unroll
  for (int i = 0; i < 2; ++i) {
    int row0 = bm * 128 + wr * 32 + i * 16 + ldiv * 4;
#pragma unroll
    for (int j = 0; j < 4; ++j) {
      int col = bn * 128 + wc * 64 + j * 16 + lmod;
#pragma unroll
      for (int r = 0; r < 4; ++r)
        C[(size_t)(row0 + r) * N + col] = (OutT)acc[i][j][r];
    }
  }
}

// ---------------------------------------------------------------- GEMM B: 4-wave (256t),
// 128x64 tile, BK=64 -> 2 blocks/CU (independent barrier domains interleave drains).
// Wave w owns rows w*32..+31, all 64 cols.
template <typename OutT>
__global__ __launch_bounds__(256) void gemm64(const __bf16* __restrict__ A,
                                              const __bf16* __restrict__ BT,
                                              OutT* __restrict__ C,
                                              int M, int N, int K) {
  __shared__ alignas(16) __bf16 As[2][128 * 64];  // 16KB/buf
  __shared__ alignas(16) __bf16 Bs[2][64 * 64];   // 8KB/buf
  int gx = gridDim.x;
  int l = blockIdx.y * gx + blockIdx.x;
  int cpx = gx >> 3;
  int xcd = l & 7, rr0 = l >> 3;
  int bn = xcd * cpx + rr0 % cpx;
  int bm = rr0 / cpx;
  int t = threadIdx.x;
  int lane = t & 63, w = t >> 6;  // 4 waves
  int lmod = lane & 15, ldiv = lane >> 4;

  f32x4 acc[2][4] = {};

  int sr8 = lane >> 3;
  int sk = (lane & 7) ^ sr8;
  const __bf16* gaB[4];
  const __bf16* gbB[2];
#pragma unroll
  for (int c = 0; c < 4; ++c) {
    int rr = (w * 4 + c) * 8 + sr8;
    gaB[c] = A + (size_t)(bm * 128 + rr) * K + sk * 8;
  }
#pragma unroll
  for (int c = 0; c < 2; ++c) {
    int rr = (w * 2 + c) * 8 + sr8;
    gbB[c] = BT + (size_t)(bn * 64 + rr) * K + sk * 8;
  }

#define GSTAGE64(buf, k0)                                              \
  {                                                                    \
    _Pragma("unroll") for (int c = 0; c < 4; ++c)                      \
        gload_lds16(gaB[c] + (k0), &As[buf][(w * 4 + c) * 512]);       \
    _Pragma("unroll") for (int c = 0; c < 2; ++c)                      \
        gload_lds16(gbB[c] + (k0), &Bs[buf][(w * 2 + c) * 512]);       \
  }

  int ca = ldiv ^ (lmod & 7);
  int cb = (4 + ldiv) ^ (lmod & 7);

  int NT = K >> 6;
  GSTAGE64(0, 0);
  int cur = 0;
  for (int tt = 0; tt < NT; ++tt) {
    __syncthreads();
    if (tt + 1 < NT) GSTAGE64(cur ^ 1, (tt + 1) * 64);

    bf16x8 af[2][2], bfv[4][2];
#pragma unroll
    for (int i = 0; i < 2; ++i) {
      const __bf16* p = &As[cur][(w * 32 + i * 16 + lmod) * 64];
      af[i][0] = *(const bf16x8*)(p + ca * 8);
      af[i][1] = *(const bf16x8*)(p + cb * 8);
    }
#pragma unroll
    for (int j = 0; j < 4; ++j) {
      const __bf16* p = &Bs[cur][(j * 16 + lmod) * 64];
      bfv[j][0] = *(const bf16x8*)(p + ca * 8);
      bfv[j][1] = *(const bf16x8*)(p + cb * 8);
    }
    __builtin_amdgcn_s_setprio(1);
#pragma unroll
    for (int i = 0; i < 2; ++i)
#pragma unroll
      for (int j = 0; j < 4; ++j) {
        acc[i][j] = MFMA16(af[i][0], bfv[j][0], acc[i][j]);
        acc[i][j] = MFMA16(af[i][1], bfv[j][1], acc[i][j]);
      }
    __builtin_amdgcn_s_setprio(0);
    cur ^= 1;
  }

#pragma unroll
  for (int i = 0; i < 2; ++i) {
    int row0 = bm * 128 + w * 32 + i * 16 + ldiv * 4;
#pragma unroll
    for (int j = 0; j < 4; ++j) {
      int col = bn * 64 + j * 16 + lmod;
#pragma unroll
      for (int r = 0; r < 4; ++r)
        C[(size_t)(row0 + r) * N + col] = (OutT)acc[i][j][r];
    }
  }
}

// ---------------------------------------------------------------- RoPE + restructure
__global__ __launch_bounds__(256) void rope_restruct(__bf16* __restrict__ qkv,
                                                     const float* __restrict__ cosb,
                                                     const float* __restrict__ sinb,
                                                     __bf16* __restrict__ Kr,
                                                     __bf16* __restrict__ Vt) {
  int st = blockIdx.x * 64;
  int kvh = blockIdx.y;
  int t = threadIdx.x;
  __shared__ alignas(16) __bf16 vtile[64][72];
  const float csq = 0.125f * LOG2E;

  int r = t >> 2;
  int q4 = t & 3;
  int s = st + r;
  const float* cp = cosb + (size_t)s * 32;
  const float* sp = sinb + (size_t)s * 32;

  float cf[32], sf[32];
#pragma unroll
  for (int c = 0; c < 8; ++c) {
    f32x4v cv = *(const f32x4v*)(cp + c * 4);
    f32x4v sv = *(const f32x4v*)(sp + c * 4);
#pragma unroll
    for (int j = 0; j < 4; ++j) { cf[c * 4 + j] = cv[j]; sf[c * 4 + j] = sv[j]; }
  }

  {  // Q rope, vectorized: head h = kvh*4 + q4
    __bf16* p = qkv + (size_t)s * 3072 + (kvh * 4 + q4) * 64;
    bf16x8 q[8];
#pragma unroll
    for (int c = 0; c < 8; ++c) q[c] = *(const bf16x8*)(p + c * 8);
    float xf[32];
#pragma unroll
    for (int c = 0; c < 4; ++c)
#pragma unroll
      for (int j = 0; j < 8; ++j) xf[c * 8 + j] = (float)q[c][j];
    bf16x8 o[8];
#pragma unroll
    for (int d = 0; d < 16; ++d) {
      float o1 = (xf[d] * cf[d] - xf[d + 16] * sf[d]) * csq;
      float o2 = (xf[d + 16] * cf[d + 16] + xf[d] * sf[d + 16]) * csq;
      o[d >> 3][d & 7] = (__bf16)o1;
      o[(d + 16) >> 3][d & 7] = (__bf16)o2;
    }
#pragma unroll
    for (int c = 4; c < 8; ++c)
#pragma unroll
      for (int j = 0; j < 8; ++j) o[c][j] = (__bf16)((float)q[c][j] * csq);
#pragma unroll
    for (int c = 0; c < 8; ++c) *(bf16x8*)(p + c * 8) = o[c];
  }
  {  // K rope -> Kr
    const __bf16* p = qkv + (size_t)s * 3072 + 2048 + kvh * 64;
    __bf16* ko = Kr + ((size_t)kvh * 2048 + s) * 64;
    if (q4 == 0) {
      bf16x8 a0 = *(const bf16x8*)p, a1 = *(const bf16x8*)(p + 8);
      bf16x8 b0 = *(const bf16x8*)(p + 16), b1 = *(const bf16x8*)(p + 24);
      bf16x8 o0, o1;
#pragma unroll
      for (int j = 0; j < 8; ++j) {
        o0[j] = (__bf16)((float)a0[j] * cf[j] - (float)b0[j] * sf[j]);
        o1[j] = (__bf16)((float)a1[j] * cf[8 + j] - (float)b1[j] * sf[8 + j]);
      }
      *(bf16x8*)ko = o0;
      *(bf16x8*)(ko + 8) = o1;
    } else if (q4 == 1) {
      bf16x8 a0 = *(const bf16x8*)p, a1 = *(const bf16x8*)(p + 8);
      bf16x8 b0 = *(const bf16x8*)(p + 16), b1 = *(const bf16x8*)(p + 24);
      bf16x8 o0, o1;
#pragma unroll
      for (int j = 0; j < 8; ++j) {
        o0[j] = (__bf16)((float)b0[j] * cf[16 + j] + (float)a0[j] * sf[16 + j]);
        o1[j] = (__bf16)((float)b1[j] * cf[24 + j] + (float)a1[j] * sf[24 + j]);
      }
      *(bf16x8*)(ko + 16) = o0;
      *(bf16x8*)(ko + 24) = o1;
    } else if (q4 == 2) {
      *(bf16x8*)(ko + 32) = *(const bf16x8*)(p + 32);
      *(bf16x8*)(ko + 40) = *(const bf16x8*)(p + 40);
    } else {
      *(bf16x8*)(ko + 48) = *(const bf16x8*)(p + 48);
      *(bf16x8*)(ko + 56) = *(const bf16x8*)(p + 56);
    }
  }
  {  // V transpose -> Vt
    const __bf16* p = qkv + (size_t)s * 3072 + 2560 + kvh * 64 + q4 * 16;
    *(bf16x8*)&vtile[r][q4 * 16] = *(const bf16x8*)p;
    *(bf16x8*)&vtile[r][q4 * 16 + 8] = *(const bf16x8*)(p + 8);
  }
  __syncthreads();
  {
    int d = t >> 2;
    __bf16* vo = Vt + ((size_t)kvh * 64 + d) * 2048 + st + q4 * 16;
#pragma unroll
    for (int j = 0; j < 16; ++j) vo[j] = vtile[q4 * 16 + j][d];
  }
}

// ---------------------------------------------------------------- flash attention v11
// Triangle-fold: block (h, b) processes q-tile b (b+1 kv tiles) THEN q-tile 31-b
// (32-b kv tiles) = exactly 33 tile-units for EVERY block -> zero tail, steady
// 8 waves/CU. Core = v6: QBLK=64, 4 waves x 16 q rows, KVBLK=64 dbuf, swapped
// QK^T, pi-permuted K staging (P regs = PV A-frag), shift-free softmax.
__global__ __launch_bounds__(256) void attn_fwd(const __bf16* __restrict__ qkv,
                                                const __bf16* __restrict__ Kr,
                                                const __bf16* __restrict__ Vt,
                                                __bf16* __restrict__ O) {
  const int S = 2048, LDQ = 3072;
  int h = blockIdx.x;
  int b = blockIdx.y;  // 0..15
  int kvh = h >> 2;
  int t = threadIdx.x;
  int lane = t & 63, w = t >> 6;  // 4 waves
  int lmod = lane & 15, ldiv = lane >> 4;

  __shared__ alignas(16) __bf16 KV[2][2][4096];  // [buf][K/V][row*64+col], 32KB

  const __bf16* Kg = Kr + (size_t)kvh * S * 64;
  const __bf16* Vg = Vt + (size_t)kvh * 64 * S;
  int srow8 = lane >> 3;          // row-within-8 of chunk
  int schk = (lane & 7) ^ srow8;  // swizzled in-row 16B-chunk index

#define STAGE(buf, ks)                                                            \
  {                                                                               \
    __bf16* kb = &KV[buf][0][0];                                                  \
    __bf16* vb = &KV[buf][1][0];                                                  \
    _Pragma("unroll") for (int c = 0; c < 2; ++c) {                               \
      int c1kb = w * 2 + c;                                                       \
      int rr = c1kb * 8 + srow8;                                                  \
      int rrg = (rr & 0x23) | ((rr & 0x0C) << 1) | ((rr & 0x10) >> 2);            \
      gload_lds16(Kg + (size_t)((ks) + rrg) * 64 + schk * 8, kb + c1kb * 512);    \
      gload_lds16(Vg + (size_t)rr * S + (ks) + schk * 8, vb + c1kb * 512);        \
    }                                                                             \
  }

  int r7 = lmod & 7;
  int ca = ldiv ^ r7;        // swizzled chunk, k-slots 0..31 half
  int cb = (4 + ldiv) ^ r7;  // k-slots 32..63 half

#pragma unroll
  for (int seg = 0; seg < 2; ++seg) {
    int qt = seg ? (31 - b) : b;
    int nkt = qt + 1;
    int R0 = qt * 64 + w * 16;  // this wave's 16 q rows

    const __bf16* qp = qkv + (size_t)(R0 + lmod) * LDQ + h * 64 + ldiv * 8;
    bf16x8 qf0 = *(const bf16x8*)qp;
    bf16x8 qf1 = *(const bf16x8*)(qp + 32);

    f32x4 acc[4] = {};
    f32x4 lacc = {};

    __syncthreads();  // protect LDS reuse across segments
    STAGE(0, 0);

    int cur = 0;
    for (int kt = 0; kt < nkt; ++kt) {
      int ks = kt * 64;
      __syncthreads();  // drains own gload vmcnt (issued one compute-phase ago)
      if (kt + 1 < nkt) STAGE(cur ^ 1, ks + 64);
      const __bf16* Ksb = &KV[cur][0][0];
      const __bf16* Vsb = &KV[cur][1][0];

      // ---- QK^T (swapped): reg (t16,r) of lane (q=lmod,d=ldiv) holds score for
      // global k = ks + 32*(t16>>1) + 4*(t16&1) + 8*d + r (pi-permuted staging).
      f32x4 st[4] = {};
      __builtin_amdgcn_s_setprio(1);
#pragma unroll
      for (int t16 = 0; t16 < 4; ++t16) {
        int row = t16 * 16 + lmod;
        bf16x8 kf0 = *(const bf16x8*)(Ksb + row * 64 + ca * 8);
        bf16x8 kf1 = *(const bf16x8*)(Ksb + row * 64 + cb * 8);
        st[t16] = MFMA16(kf0, qf0, st[t16]);
        st[t16] = MFMA16(kf1, qf1, st[t16]);
      }
      __builtin_amdgcn_s_setprio(0);

      if (kt == nkt - 1) {  // diagonal tile: causal mask (permuted k formula)
        int qq = R0 + lmod;
#pragma unroll
        for (int t16 = 0; t16 < 4; ++t16) {
          int kk = ks + (t16 >> 1) * 32 + (t16 & 1) * 4 + ldiv * 8;
#pragma unroll
          for (int r = 0; r < 4; ++r)
            st[t16][r] = (kk + r) <= qq ? st[t16][r] : -1e30f;
        }
      }

      // V fragments
      bf16x8 vf[8];
#pragma unroll
      for (int g2 = 0; g2 < 4; ++g2) {
        int row = g2 * 16 + lmod;
        vf[g2] = *(const bf16x8*)(Vsb + row * 64 + ca * 8);
        vf[4 + g2] = *(const bf16x8*)(Vsb + row * 64 + cb * 8);
      }

      // ---- shift-free softmax: p = exp2(st); per-lane partial sums
#pragma unroll
      for (int t16 = 0; t16 < 4; ++t16)
#pragma unroll
        for (int r = 0; r < 4; ++r) {
          float pv = __builtin_amdgcn_exp2f(st[t16][r]);
          st[t16][r] = pv;
          lacc[r] += pv;
        }

      // pack P: registers are already in PV A-fragment order (pi staging)
      u32x4 av0, av1;
      av0[0] = pk2(st[0][0], st[0][1]);
      av0[1] = pk2(st[0][2], st[0][3]);
      av0[2] = pk2(st[1][0], st[1][1]);
      av0[3] = pk2(st[1][2], st[1][3]);
      av1[0] = pk2(st[2][0], st[2][1]);
      av1[1] = pk2(st[2][2], st[2][3]);
      av1[2] = pk2(st[3][0], st[3][1]);
      av1[3] = pk2(st[3][2], st[3][3]);
      bf16x8 pa0 = __builtin_bit_cast(bf16x8, av0);
      bf16x8 pa1 = __builtin_bit_cast(bf16x8, av1);

      __builtin_amdgcn_s_setprio(1);
#pragma unroll
      for (int g2 = 0; g2 < 4; ++g2) {
        acc[g2] = MFMA16(pa0, vf[g2], acc[g2]);
        acc[g2] = MFMA16(pa1, vf[4 + g2], acc[g2]);
      }
      __builtin_amdgcn_s_setprio(0);
      cur ^= 1;
    }

    // epilogue: reduce l across lanes once, then normalize
    {
      float lsum = lacc[0] + lacc[1] + lacc[2] + lacc[3];
      lsum += __shfl_xor(lsum, 16);
      lsum += __shfl_xor(lsum, 32);
      float linv[4];
#pragma unroll
      for (int r = 0; r < 4; ++r) {
        float lq = __shfl(lsum, ldiv * 4 + r);
        linv[r] = 1.0f / lq;
      }
#pragma unroll
      for (int g2 = 0; g2 < 4; ++g2)
#pragma unroll
        for (int r = 0; r < 4; ++r)
          O[(size_t)(R0 + ldiv * 4 + r) * 2048 + h * 64 + g2 * 16 + lmod] =
              (__bf16)(acc[g2][r] * linv[r]);
    }
  }
}

// ---------------------------------------------------------------- launch
extern "C" void kernel_launch(void* const* d_in, const int* in_sizes, int n_in,
                              void* d_out, int out_size, void* d_ws, size_t ws_size,
                              hipStream_t stream) {
  const float* x = (const float*)d_in[0];
  const float* cosb = (const float*)d_in[1];
  const float* sinb = (const float*)d_in[2];
  const float* wqkv = (const float*)d_in[3];
  const float* wo = (const float*)d_in[4];
  float* out = (float*)d_out;

  char* ws = (char*)d_ws;
  __bf16* xb    = (__bf16*)(ws + 0);
  __bf16* wqkvT = (__bf16*)(ws + 8388608);
  __bf16* woT   = (__bf16*)(ws + 20971520);
  __bf16* qkvb  = (__bf16*)(ws + 29360128);
  __bf16* Krb   = (__bf16*)(ws + 41943040);
  __bf16* Vtb   = (__bf16*)(ws + 44040192);
  __bf16* attnb = (__bf16*)(ws + 46137344);

  prep<<<6656, 256, 0, stream>>>(x, xb, wqkv, wqkvT, wo, woT);
  gemm8w<__bf16><<<dim3(24, 16), 512, 0, stream>>>(xb, wqkvT, qkvb, 2048, 3072, 2048);
  rope_restruct<<<dim3(32, 8), 256, 0, stream>>>(qkvb, cosb, sinb, Krb, Vtb);
  attn_fwd<<<dim3(32, 16), 256, 0, stream>>>(qkvb, Krb, Vtb, attnb);
  gemm64<float><<<dim3(32, 16), 256, 0, stream>>>(attnb, woT, out, 2048, 2048, 2048);
}

// Round 14
// 113.925 us; speedup vs baseline: 1.2220x; 1.0219x over previous
//
#include <hip/hip_runtime.h>
#include <hip/hip_bf16.h>
#include <stdint.h>

typedef float f32x4 __attribute__((ext_vector_type(4)));
typedef float f32x4v __attribute__((ext_vector_type(4)));
typedef __bf16 bf16x8 __attribute__((ext_vector_type(8)));
typedef __bf16 bf16x4 __attribute__((ext_vector_type(4)));
typedef __bf16 bf16x2 __attribute__((ext_vector_type(2)));
typedef unsigned int u32x4 __attribute__((ext_vector_type(4)));

#define LOG2E 1.44269504088896340736f
#define MFMA16(a, b, c) __builtin_amdgcn_mfma_f32_16x16x32_bf16((a), (b), (c), 0, 0, 0)

static __device__ __forceinline__ void gload_lds16(const void* g, void* l) {
  __builtin_amdgcn_global_load_lds(
      (const __attribute__((address_space(1))) unsigned int*)g,
      (__attribute__((address_space(3))) unsigned int*)l, 16, 0, 0);
}

static __device__ __forceinline__ uint32_t pk2(float lo, float hi) {
  bf16x2 v;
  v[0] = (__bf16)lo;
  v[1] = (__bf16)hi;
  return __builtin_bit_cast(uint32_t, v);
}

// ---------------------------------------------------------------- prep: cvt + both transposes
__global__ __launch_bounds__(256) void prep(const float* __restrict__ x,
                                            __bf16* __restrict__ xb,
                                            const float* __restrict__ wqkv,
                                            __bf16* __restrict__ wqkvT,
                                            const float* __restrict__ wo,
                                            __bf16* __restrict__ woT) {
  __shared__ float tile[64][65];
  int b = blockIdx.x;
  int t = threadIdx.x;
  if (b < 4096) {
    int i = b * 256 + t;
    f32x4v v = *(const f32x4v*)(x + (size_t)i * 4);
    bf16x4 o;
    o[0] = (__bf16)v[0]; o[1] = (__bf16)v[1]; o[2] = (__bf16)v[2]; o[3] = (__bf16)v[3];
    *(bf16x4*)(xb + (size_t)i * 4) = o;
    return;
  }
  const float* in;
  __bf16* out;
  int R, C, bx, by;
  if (b < 5632) {
    int bb = b - 4096;
    in = wqkv; out = wqkvT; R = 2048; C = 3072; bx = bb % 48; by = bb / 48;
  } else {
    int bb = b - 5632;
    in = wo; out = woT; R = 2048; C = 2048; bx = bb & 31; by = bb >> 5;
  }
  int tr = by * 64, tc = bx * 64;
  int r0 = t >> 4;
  int c4 = (t & 15) * 4;
#pragma unroll
  for (int i = 0; i < 4; ++i) {
    int r = r0 + i * 16;
    f32x4v v = *(const f32x4v*)(in + (size_t)(tr + r) * C + tc + c4);
    tile[r][c4 + 0] = v[0]; tile[r][c4 + 1] = v[1];
    tile[r][c4 + 2] = v[2]; tile[r][c4 + 3] = v[3];
  }
  __syncthreads();
#pragma unroll
  for (int i = 0; i < 4; ++i) {
    int r = r0 + i * 16;
    __bf16* o = out + (size_t)(tc + r) * R + tr + c4;
    bf16x4 ov;
    ov[0] = (__bf16)tile[c4 + 0][r]; ov[1] = (__bf16)tile[c4 + 1][r];
    ov[2] = (__bf16)tile[c4 + 2][r]; ov[3] = (__bf16)tile[c4 + 3][r];
    *(bf16x4*)o = ov;
  }
}

// ---------------------------------------------------------------- GEMM: 4-wave (256t),
// 128x64 tile, BK=64, 1-barrier dbuf, XOR-swizzled LDS, XCD swizzle (gx%8==0).
// 48KB LDS -> 3 blocks/CU. Wave w owns rows w*32..+31, all 64 cols.
template <typename OutT>
__global__ __launch_bounds__(256) void gemm64(const __bf16* __restrict__ A,
                                              const __bf16* __restrict__ BT,
                                              OutT* __restrict__ C,
                                              int M, int N, int K) {
  __shared__ alignas(16) __bf16 As[2][128 * 64];  // 16KB/buf
  __shared__ alignas(16) __bf16 Bs[2][64 * 64];   // 8KB/buf
  int gx = gridDim.x;
  int l = blockIdx.y * gx + blockIdx.x;
  int cpx = gx >> 3;
  int xcd = l & 7, rr0 = l >> 3;
  int bn = xcd * cpx + rr0 % cpx;
  int bm = rr0 / cpx;
  int t = threadIdx.x;
  int lane = t & 63, w = t >> 6;  // 4 waves
  int lmod = lane & 15, ldiv = lane >> 4;

  f32x4 acc[2][4] = {};

  int sr8 = lane >> 3;
  int sk = (lane & 7) ^ sr8;
  const __bf16* gaB[4];
  const __bf16* gbB[2];
#pragma unroll
  for (int c = 0; c < 4; ++c) {
    int rr = (w * 4 + c) * 8 + sr8;
    gaB[c] = A + (size_t)(bm * 128 + rr) * K + sk * 8;
  }
#pragma unroll
  for (int c = 0; c < 2; ++c) {
    int rr = (w * 2 + c) * 8 + sr8;
    gbB[c] = BT + (size_t)(bn * 64 + rr) * K + sk * 8;
  }

#define GSTAGE64(buf, k0)                                              \
  {                                                                    \
    _Pragma("unroll") for (int c = 0; c < 4; ++c)                      \
        gload_lds16(gaB[c] + (k0), &As[buf][(w * 4 + c) * 512]);       \
    _Pragma("unroll") for (int c = 0; c < 2; ++c)                      \
        gload_lds16(gbB[c] + (k0), &Bs[buf][(w * 2 + c) * 512]);       \
  }

  int ca = ldiv ^ (lmod & 7);
  int cb = (4 + ldiv) ^ (lmod & 7);

  int NT = K >> 6;
  GSTAGE64(0, 0);
  int cur = 0;
  for (int tt = 0; tt < NT; ++tt) {
    __syncthreads();
    if (tt + 1 < NT) GSTAGE64(cur ^ 1, (tt + 1) * 64);

    bf16x8 af[2][2], bfv[4][2];
#pragma unroll
    for (int i = 0; i < 2; ++i) {
      const __bf16* p = &As[cur][(w * 32 + i * 16 + lmod) * 64];
      af[i][0] = *(const bf16x8*)(p + ca * 8);
      af[i][1] = *(const bf16x8*)(p + cb * 8);
    }
#pragma unroll
    for (int j = 0; j < 4; ++j) {
      const __bf16* p = &Bs[cur][(j * 16 + lmod) * 64];
      bfv[j][0] = *(const bf16x8*)(p + ca * 8);
      bfv[j][1] = *(const bf16x8*)(p + cb * 8);
    }
    __builtin_amdgcn_s_setprio(1);
#pragma unroll
    for (int i = 0; i < 2; ++i)
#pragma unroll
      for (int j = 0; j < 4; ++j) {
        acc[i][j] = MFMA16(af[i][0], bfv[j][0], acc[i][j]);
        acc[i][j] = MFMA16(af[i][1], bfv[j][1], acc[i][j]);
      }
    __builtin_amdgcn_s_setprio(0);
    cur ^= 1;
  }

#pragma unroll
  for (int i = 0; i < 2; ++i) {
    int row0 = bm * 128 + w * 32 + i * 16 + ldiv * 4;
#pragma unroll
    for (int j = 0; j < 4; ++j) {
      int col = bn * 64 + j * 16 + lmod;
#pragma unroll
      for (int r = 0; r < 4; ++r)
        C[(size_t)(row0 + r) * N + col] = (OutT)acc[i][j][r];
    }
  }
}

// ---------------------------------------------------------------- RoPE + restructure
__global__ __launch_bounds__(256) void rope_restruct(__bf16* __restrict__ qkv,
                                                     const float* __restrict__ cosb,
                                                     const float* __restrict__ sinb,
                                                     __bf16* __restrict__ Kr,
                                                     __bf16* __restrict__ Vt) {
  int st = blockIdx.x * 64;
  int kvh = blockIdx.y;
  int t = threadIdx.x;
  __shared__ alignas(16) __bf16 vtile[64][72];
  const float csq = 0.125f * LOG2E;

  int r = t >> 2;
  int q4 = t & 3;
  int s = st + r;
  const float* cp = cosb + (size_t)s * 32;
  const float* sp = sinb + (size_t)s * 32;

  float cf[32], sf[32];
#pragma unroll
  for (int c = 0; c < 8; ++c) {
    f32x4v cv = *(const f32x4v*)(cp + c * 4);
    f32x4v sv = *(const f32x4v*)(sp + c * 4);
#pragma unroll
    for (int j = 0; j < 4; ++j) { cf[c * 4 + j] = cv[j]; sf[c * 4 + j] = sv[j]; }
  }

  {  // Q rope, vectorized: head h = kvh*4 + q4
    __bf16* p = qkv + (size_t)s * 3072 + (kvh * 4 + q4) * 64;
    bf16x8 q[8];
#pragma unroll
    for (int c = 0; c < 8; ++c) q[c] = *(const bf16x8*)(p + c * 8);
    float xf[32];
#pragma unroll
    for (int c = 0; c < 4; ++c)
#pragma unroll
      for (int j = 0; j < 8; ++j) xf[c * 8 + j] = (float)q[c][j];
    bf16x8 o[8];
#pragma unroll
    for (int d = 0; d < 16; ++d) {
      float o1 = (xf[d] * cf[d] - xf[d + 16] * sf[d]) * csq;
      float o2 = (xf[d + 16] * cf[d + 16] + xf[d] * sf[d + 16]) * csq;
      o[d >> 3][d & 7] = (__bf16)o1;
      o[(d + 16) >> 3][d & 7] = (__bf16)o2;
    }
#pragma unroll
    for (int c = 4; c < 8; ++c)
#pragma unroll
      for (int j = 0; j < 8; ++j) o[c][j] = (__bf16)((float)q[c][j] * csq);
#pragma unroll
    for (int c = 0; c < 8; ++c) *(bf16x8*)(p + c * 8) = o[c];
  }
  {  // K rope -> Kr
    const __bf16* p = qkv + (size_t)s * 3072 + 2048 + kvh * 64;
    __bf16* ko = Kr + ((size_t)kvh * 2048 + s) * 64;
    if (q4 == 0) {
      bf16x8 a0 = *(const bf16x8*)p, a1 = *(const bf16x8*)(p + 8);
      bf16x8 b0 = *(const bf16x8*)(p + 16), b1 = *(const bf16x8*)(p + 24);
      bf16x8 o0, o1;
#pragma unroll
      for (int j = 0; j < 8; ++j) {
        o0[j] = (__bf16)((float)a0[j] * cf[j] - (float)b0[j] * sf[j]);
        o1[j] = (__bf16)((float)a1[j] * cf[8 + j] - (float)b1[j] * sf[8 + j]);
      }
      *(bf16x8*)ko = o0;
      *(bf16x8*)(ko + 8) = o1;
    } else if (q4 == 1) {
      bf16x8 a0 = *(const bf16x8*)p, a1 = *(const bf16x8*)(p + 8);
      bf16x8 b0 = *(const bf16x8*)(p + 16), b1 = *(const bf16x8*)(p + 24);
      bf16x8 o0, o1;
#pragma unroll
      for (int j = 0; j < 8; ++j) {
        o0[j] = (__bf16)((float)b0[j] * cf[16 + j] + (float)a0[j] * sf[16 + j]);
        o1[j] = (__bf16)((float)b1[j] * cf[24 + j] + (float)a1[j] * sf[24 + j]);
      }
      *(bf16x8*)(ko + 16) = o0;
      *(bf16x8*)(ko + 24) = o1;
    } else if (q4 == 2) {
      *(bf16x8*)(ko + 32) = *(const bf16x8*)(p + 32);
      *(bf16x8*)(ko + 40) = *(const bf16x8*)(p + 40);
    } else {
      *(bf16x8*)(ko + 48) = *(const bf16x8*)(p + 48);
      *(bf16x8*)(ko + 56) = *(const bf16x8*)(p + 56);
    }
  }
  {  // V transpose -> Vt
    const __bf16* p = qkv + (size_t)s * 3072 + 2560 + kvh * 64 + q4 * 16;
    *(bf16x8*)&vtile[r][q4 * 16] = *(const bf16x8*)p;
    *(bf16x8*)&vtile[r][q4 * 16 + 8] = *(const bf16x8*)(p + 8);
  }
  __syncthreads();
  {
    int d = t >> 2;
    __bf16* vo = Vt + ((size_t)kvh * 64 + d) * 2048 + st + q4 * 16;
#pragma unroll
    for (int j = 0; j < 16; ++j) vo[j] = vtile[q4 * 16 + j][d];
  }
}

// ---------------------------------------------------------------- flash attention v11
// Triangle-fold: block (h, b) processes q-tile b (b+1 kv tiles) THEN q-tile 31-b
// (32-b kv tiles) = exactly 33 tile-units for EVERY block -> zero tail, steady
// 8 waves/CU. Core = v6: QBLK=64, 4 waves x 16 q rows, KVBLK=64 dbuf, swapped
// QK^T, pi-permuted K staging (P regs = PV A-frag), shift-free softmax.
__global__ __launch_bounds__(256) void attn_fwd(const __bf16* __restrict__ qkv,
                                                const __bf16* __restrict__ Kr,
                                                const __bf16* __restrict__ Vt,
                                                __bf16* __restrict__ O) {
  const int S = 2048, LDQ = 3072;
  int h = blockIdx.x;
  int b = blockIdx.y;  // 0..15
  int kvh = h >> 2;
  int t = threadIdx.x;
  int lane = t & 63, w = t >> 6;  // 4 waves
  int lmod = lane & 15, ldiv = lane >> 4;

  __shared__ alignas(16) __bf16 KV[2][2][4096];  // [buf][K/V][row*64+col], 32KB

  const __bf16* Kg = Kr + (size_t)kvh * S * 64;
  const __bf16* Vg = Vt + (size_t)kvh * 64 * S;
  int srow8 = lane >> 3;          // row-within-8 of chunk
  int schk = (lane & 7) ^ srow8;  // swizzled in-row 16B-chunk index

#define STAGE(buf, ks)                                                            \
  {                                                                               \
    __bf16* kb = &KV[buf][0][0];                                                  \
    __bf16* vb = &KV[buf][1][0];                                                  \
    _Pragma("unroll") for (int c = 0; c < 2; ++c) {                               \
      int c1kb = w * 2 + c;                                                       \
      int rr = c1kb * 8 + srow8;                                                  \
      int rrg = (rr & 0x23) | ((rr & 0x0C) << 1) | ((rr & 0x10) >> 2);            \
      gload_lds16(Kg + (size_t)((ks) + rrg) * 64 + schk * 8, kb + c1kb * 512);    \
      gload_lds16(Vg + (size_t)rr * S + (ks) + schk * 8, vb + c1kb * 512);        \
    }                                                                             \
  }

  int r7 = lmod & 7;
  int ca = ldiv ^ r7;        // swizzled chunk, k-slots 0..31 half
  int cb = (4 + ldiv) ^ r7;  // k-slots 32..63 half

#pragma unroll
  for (int seg = 0; seg < 2; ++seg) {
    int qt = seg ? (31 - b) : b;
    int nkt = qt + 1;
    int R0 = qt * 64 + w * 16;  // this wave's 16 q rows

    const __bf16* qp = qkv + (size_t)(R0 + lmod) * LDQ + h * 64 + ldiv * 8;
    bf16x8 qf0 = *(const bf16x8*)qp;
    bf16x8 qf1 = *(const bf16x8*)(qp + 32);

    f32x4 acc[4] = {};
    f32x4 lacc = {};

    __syncthreads();  // protect LDS reuse across segments
    STAGE(0, 0);

    int cur = 0;
    for (int kt = 0; kt < nkt; ++kt) {
      int ks = kt * 64;
      __syncthreads();  // drains own gload vmcnt (issued one compute-phase ago)
      if (kt + 1 < nkt) STAGE(cur ^ 1, ks + 64);
      const __bf16* Ksb = &KV[cur][0][0];
      const __bf16* Vsb = &KV[cur][1][0];

      // ---- QK^T (swapped): reg (t16,r) of lane (q=lmod,d=ldiv) holds score for
      // global k = ks + 32*(t16>>1) + 4*(t16&1) + 8*d + r (pi-permuted staging).
      f32x4 st[4] = {};
      __builtin_amdgcn_s_setprio(1);
#pragma unroll
      for (int t16 = 0; t16 < 4; ++t16) {
        int row = t16 * 16 + lmod;
        bf16x8 kf0 = *(const bf16x8*)(Ksb + row * 64 + ca * 8);
        bf16x8 kf1 = *(const bf16x8*)(Ksb + row * 64 + cb * 8);
        st[t16] = MFMA16(kf0, qf0, st[t16]);
        st[t16] = MFMA16(kf1, qf1, st[t16]);
      }
      __builtin_amdgcn_s_setprio(0);

      if (kt == nkt - 1) {  // diagonal tile: causal mask (permuted k formula)
        int qq = R0 + lmod;
#pragma unroll
        for (int t16 = 0; t16 < 4; ++t16) {
          int kk = ks + (t16 >> 1) * 32 + (t16 & 1) * 4 + ldiv * 8;
#pragma unroll
          for (int r = 0; r < 4; ++r)
            st[t16][r] = (kk + r) <= qq ? st[t16][r] : -1e30f;
        }
      }

      // V fragments
      bf16x8 vf[8];
#pragma unroll
      for (int g2 = 0; g2 < 4; ++g2) {
        int row = g2 * 16 + lmod;
        vf[g2] = *(const bf16x8*)(Vsb + row * 64 + ca * 8);
        vf[4 + g2] = *(const bf16x8*)(Vsb + row * 64 + cb * 8);
      }

      // ---- shift-free softmax: p = exp2(st); per-lane partial sums
#pragma unroll
      for (int t16 = 0; t16 < 4; ++t16)
#pragma unroll
        for (int r = 0; r < 4; ++r) {
          float pv = __builtin_amdgcn_exp2f(st[t16][r]);
          st[t16][r] = pv;
          lacc[r] += pv;
        }

      // pack P: registers are already in PV A-fragment order (pi staging)
      u32x4 av0, av1;
      av0[0] = pk2(st[0][0], st[0][1]);
      av0[1] = pk2(st[0][2], st[0][3]);
      av0[2] = pk2(st[1][0], st[1][1]);
      av0[3] = pk2(st[1][2], st[1][3]);
      av1[0] = pk2(st[2][0], st[2][1]);
      av1[1] = pk2(st[2][2], st[2][3]);
      av1[2] = pk2(st[3][0], st[3][1]);
      av1[3] = pk2(st[3][2], st[3][3]);
      bf16x8 pa0 = __builtin_bit_cast(bf16x8, av0);
      bf16x8 pa1 = __builtin_bit_cast(bf16x8, av1);

      __builtin_amdgcn_s_setprio(1);
#pragma unroll
      for (int g2 = 0; g2 < 4; ++g2) {
        acc[g2] = MFMA16(pa0, vf[g2], acc[g2]);
        acc[g2] = MFMA16(pa1, vf[4 + g2], acc[g2]);
      }
      __builtin_amdgcn_s_setprio(0);
      cur ^= 1;
    }

    // epilogue: reduce l across lanes once, then normalize
    {
      float lsum = lacc[0] + lacc[1] + lacc[2] + lacc[3];
      lsum += __shfl_xor(lsum, 16);
      lsum += __shfl_xor(lsum, 32);
      float linv[4];
#pragma unroll
      for (int r = 0; r < 4; ++r) {
        float lq = __shfl(lsum, ldiv * 4 + r);
        linv[r] = 1.0f / lq;
      }
#pragma unroll
      for (int g2 = 0; g2 < 4; ++g2)
#pragma unroll
        for (int r = 0; r < 4; ++r)
          O[(size_t)(R0 + ldiv * 4 + r) * 2048 + h * 64 + g2 * 16 + lmod] =
              (__bf16)(acc[g2][r] * linv[r]);
    }
  }
}

// ---------------------------------------------------------------- launch
extern "C" void kernel_launch(void* const* d_in, const int* in_sizes, int n_in,
                              void* d_out, int out_size, void* d_ws, size_t ws_size,
                              hipStream_t stream) {
  const float* x = (const float*)d_in[0];
  const float* cosb = (const float*)d_in[1];
  const float* sinb = (const float*)d_in[2];
  const float* wqkv = (const float*)d_in[3];
  const float* wo = (const float*)d_in[4];
  float* out = (float*)d_out;

  char* ws = (char*)d_ws;
  __bf16* xb    = (__bf16*)(ws + 0);
  __bf16* wqkvT = (__bf16*)(ws + 8388608);
  __bf16* woT   = (__bf16*)(ws + 20971520);
  __bf16* qkvb  = (__bf16*)(ws + 29360128);
  __bf16* Krb   = (__bf16*)(ws + 41943040);
  __bf16* Vtb   = (__bf16*)(ws + 44040192);
  __bf16* attnb = (__bf16*)(ws + 46137344);

  prep<<<6656, 256, 0, stream>>>(x, xb, wqkv, wqkvT, wo, woT);
  gemm64<__bf16><<<dim3(48, 16), 256, 0, stream>>>(xb, wqkvT, qkvb, 2048, 3072, 2048);
  rope_restruct<<<dim3(32, 8), 256, 0, stream>>>(qkvb, cosb, sinb, Krb, Vtb);
  attn_fwd<<<dim3(32, 16), 256, 0, stream>>>(qkvb, Krb, Vtb, attnb);
  gemm64<float><<<dim3(32, 16), 256, 0, stream>>>(attnb, woT, out, 2048, 2048, 2048);
}

// Round 15
// 106.969 us; speedup vs baseline: 1.3015x; 1.0650x over previous
//
#include <hip/hip_runtime.h>
#include <hip/hip_bf16.h>
#include <stdint.h>

typedef float f32x4 __attribute__((ext_vector_type(4)));
typedef float f32x4v __attribute__((ext_vector_type(4)));
typedef __bf16 bf16x8 __attribute__((ext_vector_type(8)));
typedef __bf16 bf16x4 __attribute__((ext_vector_type(4)));
typedef __bf16 bf16x2 __attribute__((ext_vector_type(2)));
typedef unsigned int u32x4 __attribute__((ext_vector_type(4)));

#define LOG2E 1.44269504088896340736f
#define MFMA16(a, b, c) __builtin_amdgcn_mfma_f32_16x16x32_bf16((a), (b), (c), 0, 0, 0)

static __device__ __forceinline__ void gload_lds16(const void* g, void* l) {
  __builtin_amdgcn_global_load_lds(
      (const __attribute__((address_space(1))) unsigned int*)g,
      (__attribute__((address_space(3))) unsigned int*)l, 16, 0, 0);
}

static __device__ __forceinline__ uint32_t pk2(float lo, float hi) {
  bf16x2 v;
  v[0] = (__bf16)lo;
  v[1] = (__bf16)hi;
  return __builtin_bit_cast(uint32_t, v);
}

// ---------------------------------------------------------------- prep: cvt + both transposes
__global__ __launch_bounds__(256) void prep(const float* __restrict__ x,
                                            __bf16* __restrict__ xb,
                                            const float* __restrict__ wqkv,
                                            __bf16* __restrict__ wqkvT,
                                            const float* __restrict__ wo,
                                            __bf16* __restrict__ woT) {
  __shared__ float tile[64][65];
  int b = blockIdx.x;
  int t = threadIdx.x;
  if (b < 4096) {
    int i = b * 256 + t;
    f32x4v v = *(const f32x4v*)(x + (size_t)i * 4);
    bf16x4 o;
    o[0] = (__bf16)v[0]; o[1] = (__bf16)v[1]; o[2] = (__bf16)v[2]; o[3] = (__bf16)v[3];
    *(bf16x4*)(xb + (size_t)i * 4) = o;
    return;
  }
  const float* in;
  __bf16* out;
  int R, C, bx, by;
  if (b < 5632) {
    int bb = b - 4096;
    in = wqkv; out = wqkvT; R = 2048; C = 3072; bx = bb % 48; by = bb / 48;
  } else {
    int bb = b - 5632;
    in = wo; out = woT; R = 2048; C = 2048; bx = bb & 31; by = bb >> 5;
  }
  int tr = by * 64, tc = bx * 64;
  int r0 = t >> 4;
  int c4 = (t & 15) * 4;
#pragma unroll
  for (int i = 0; i < 4; ++i) {
    int r = r0 + i * 16;
    f32x4v v = *(const f32x4v*)(in + (size_t)(tr + r) * C + tc + c4);
    tile[r][c4 + 0] = v[0]; tile[r][c4 + 1] = v[1];
    tile[r][c4 + 2] = v[2]; tile[r][c4 + 3] = v[3];
  }
  __syncthreads();
#pragma unroll
  for (int i = 0; i < 4; ++i) {
    int r = r0 + i * 16;
    __bf16* o = out + (size_t)(tc + r) * R + tr + c4;
    bf16x4 ov;
    ov[0] = (__bf16)tile[c4 + 0][r]; ov[1] = (__bf16)tile[c4 + 1][r];
    ov[2] = (__bf16)tile[c4 + 2][r]; ov[3] = (__bf16)tile[c4 + 3][r];
    *(bf16x4*)o = ov;
  }
}

// ---------------------------------------------------------------- GEMM: 4-wave (256t),
// 128x64 tile, BK=64, 1-barrier dbuf, XOR-swizzled LDS, XCD swizzle (gx%8==0).
template <typename OutT>
__global__ __launch_bounds__(256) void gemm64(const __bf16* __restrict__ A,
                                              const __bf16* __restrict__ BT,
                                              OutT* __restrict__ C,
                                              int M, int N, int K) {
  __shared__ alignas(16) __bf16 As[2][128 * 64];
  __shared__ alignas(16) __bf16 Bs[2][64 * 64];
  int gx = gridDim.x;
  int l = blockIdx.y * gx + blockIdx.x;
  int cpx = gx >> 3;
  int xcd = l & 7, rr0 = l >> 3;
  int bn = xcd * cpx + rr0 % cpx;
  int bm = rr0 / cpx;
  int t = threadIdx.x;
  int lane = t & 63, w = t >> 6;  // 4 waves
  int lmod = lane & 15, ldiv = lane >> 4;

  f32x4 acc[2][4] = {};

  int sr8 = lane >> 3;
  int sk = (lane & 7) ^ sr8;
  const __bf16* gaB[4];
  const __bf16* gbB[2];
#pragma unroll
  for (int c = 0; c < 4; ++c) {
    int rr = (w * 4 + c) * 8 + sr8;
    gaB[c] = A + (size_t)(bm * 128 + rr) * K + sk * 8;
  }
#pragma unroll
  for (int c = 0; c < 2; ++c) {
    int rr = (w * 2 + c) * 8 + sr8;
    gbB[c] = BT + (size_t)(bn * 64 + rr) * K + sk * 8;
  }

#define GSTAGE64(buf, k0)                                              \
  {                                                                    \
    _Pragma("unroll") for (int c = 0; c < 4; ++c)                      \
        gload_lds16(gaB[c] + (k0), &As[buf][(w * 4 + c) * 512]);       \
    _Pragma("unroll") for (int c = 0; c < 2; ++c)                      \
        gload_lds16(gbB[c] + (k0), &Bs[buf][(w * 2 + c) * 512]);       \
  }

  int ca = ldiv ^ (lmod & 7);
  int cb = (4 + ldiv) ^ (lmod & 7);

  int NT = K >> 6;
  GSTAGE64(0, 0);
  int cur = 0;
  for (int tt = 0; tt < NT; ++tt) {
    __syncthreads();
    if (tt + 1 < NT) GSTAGE64(cur ^ 1, (tt + 1) * 64);

    bf16x8 af[2][2], bfv[4][2];
#pragma unroll
    for (int i = 0; i < 2; ++i) {
      const __bf16* p = &As[cur][(w * 32 + i * 16 + lmod) * 64];
      af[i][0] = *(const bf16x8*)(p + ca * 8);
      af[i][1] = *(const bf16x8*)(p + cb * 8);
    }
#pragma unroll
    for (int j = 0; j < 4; ++j) {
      const __bf16* p = &Bs[cur][(j * 16 + lmod) * 64];
      bfv[j][0] = *(const bf16x8*)(p + ca * 8);
      bfv[j][1] = *(const bf16x8*)(p + cb * 8);
    }
    __builtin_amdgcn_s_setprio(1);
#pragma unroll
    for (int i = 0; i < 2; ++i)
#pragma unroll
      for (int j = 0; j < 4; ++j) {
        acc[i][j] = MFMA16(af[i][0], bfv[j][0], acc[i][j]);
        acc[i][j] = MFMA16(af[i][1], bfv[j][1], acc[i][j]);
      }
    __builtin_amdgcn_s_setprio(0);
    cur ^= 1;
  }

#pragma unroll
  for (int i = 0; i < 2; ++i) {
    int row0 = bm * 128 + w * 32 + i * 16 + ldiv * 4;
#pragma unroll
    for (int j = 0; j < 4; ++j) {
      int col = bn * 64 + j * 16 + lmod;
#pragma unroll
      for (int r = 0; r < 4; ++r)
        C[(size_t)(row0 + r) * N + col] = (OutT)acc[i][j][r];
    }
  }
}
#undef GSTAGE64

// ---------------------------------------------------------------- GEMM1 fused with RoPE:
// same 128x64 / 4-wave / BK=64 structure; bn tile == one head (N=3072 = 48x64).
// bn<32: Q -> rope+csq-scale -> qkvb. 32<=bn<40: K -> rope -> Kr[kvh][s][64].
// bn>=40: V -> LDS-bounce transpose -> Vt[kvh][d][2048].
__global__ __launch_bounds__(256) void gemm_qkv(const __bf16* __restrict__ A,
                                                const __bf16* __restrict__ BT,
                                                __bf16* __restrict__ qkvb,
                                                __bf16* __restrict__ Kr,
                                                __bf16* __restrict__ Vt,
                                                const float* __restrict__ cosb,
                                                const float* __restrict__ sinb,
                                                int M, int K) {
  __shared__ alignas(16) __bf16 As[2][128 * 64];
  __shared__ alignas(16) __bf16 Bs[2][64 * 64];
  int gx = gridDim.x;  // 48
  int l = blockIdx.y * gx + blockIdx.x;
  int cpx = gx >> 3;
  int xcd = l & 7, rr0 = l >> 3;
  int bn = xcd * cpx + rr0 % cpx;
  int bm = rr0 / cpx;
  int t = threadIdx.x;
  int lane = t & 63, w = t >> 6;  // 4 waves
  int lmod = lane & 15, ldiv = lane >> 4;

  f32x4 acc[2][4] = {};

  int sr8 = lane >> 3;
  int sk = (lane & 7) ^ sr8;
  const __bf16* gaB[4];
  const __bf16* gbB[2];
#pragma unroll
  for (int c = 0; c < 4; ++c) {
    int rr = (w * 4 + c) * 8 + sr8;
    gaB[c] = A + (size_t)(bm * 128 + rr) * K + sk * 8;
  }
#pragma unroll
  for (int c = 0; c < 2; ++c) {
    int rr = (w * 2 + c) * 8 + sr8;
    gbB[c] = BT + (size_t)(bn * 64 + rr) * K + sk * 8;
  }

#define GSTAGEQ(buf, k0)                                               \
  {                                                                    \
    _Pragma("unroll") for (int c = 0; c < 4; ++c)                      \
        gload_lds16(gaB[c] + (k0), &As[buf][(w * 4 + c) * 512]);       \
    _Pragma("unroll") for (int c = 0; c < 2; ++c)                      \
        gload_lds16(gbB[c] + (k0), &Bs[buf][(w * 2 + c) * 512]);       \
  }

  int ca = ldiv ^ (lmod & 7);
  int cb = (4 + ldiv) ^ (lmod & 7);

  int NT = K >> 6;
  GSTAGEQ(0, 0);
  int cur = 0;
  for (int tt = 0; tt < NT; ++tt) {
    __syncthreads();
    if (tt + 1 < NT) GSTAGEQ(cur ^ 1, (tt + 1) * 64);

    bf16x8 af[2][2], bfv[4][2];
#pragma unroll
    for (int i = 0; i < 2; ++i) {
      const __bf16* p = &As[cur][(w * 32 + i * 16 + lmod) * 64];
      af[i][0] = *(const bf16x8*)(p + ca * 8);
      af[i][1] = *(const bf16x8*)(p + cb * 8);
    }
#pragma unroll
    for (int j = 0; j < 4; ++j) {
      const __bf16* p = &Bs[cur][(j * 16 + lmod) * 64];
      bfv[j][0] = *(const bf16x8*)(p + ca * 8);
      bfv[j][1] = *(const bf16x8*)(p + cb * 8);
    }
    __builtin_amdgcn_s_setprio(1);
#pragma unroll
    for (int i = 0; i < 2; ++i)
#pragma unroll
      for (int j = 0; j < 4; ++j) {
        acc[i][j] = MFMA16(af[i][0], bfv[j][0], acc[i][j]);
        acc[i][j] = MFMA16(af[i][1], bfv[j][1], acc[i][j]);
      }
    __builtin_amdgcn_s_setprio(0);
    cur ^= 1;
  }
#undef GSTAGEQ

  const float csq = 0.125f * LOG2E;
  if (bn < 40) {
    // Q or K head tile: rope pair (d, d+16) = (acc[i][0], acc[i][1]) same lane.
    bool isQ = (bn < 32);
    float sc = isQ ? csq : 1.0f;
#pragma unroll
    for (int i = 0; i < 2; ++i)
#pragma unroll
      for (int r = 0; r < 4; ++r) {
        int s = bm * 128 + w * 32 + i * 16 + ldiv * 4 + r;
        const float* cp = cosb + (size_t)s * 32;
        const float* sp = sinb + (size_t)s * 32;
        float c0 = cp[lmod], c1 = cp[16 + lmod];
        float s0 = sp[lmod], s1 = sp[16 + lmod];
        float a0 = acc[i][0][r], a1 = acc[i][1][r];
        float o0 = (a0 * c0 - a1 * s0) * sc;
        float o1 = (a1 * c1 + a0 * s1) * sc;
        float o2 = acc[i][2][r] * sc;
        float o3 = acc[i][3][r] * sc;
        __bf16* dst = isQ ? (qkvb + (size_t)s * 3072 + bn * 64)
                          : (Kr + ((size_t)(bn - 32) * 2048 + s) * 64);
        dst[lmod] = (__bf16)o0;
        dst[16 + lmod] = (__bf16)o1;
        dst[32 + lmod] = (__bf16)o2;
        dst[48 + lmod] = (__bf16)o3;
      }
  } else {
    // V head tile: transpose 128x64 -> Vt[kvh][col][row] via LDS bounce.
    int kvh = bn - 40;
    __bf16* tr = &As[0][0];  // 64 cols x 136-stride = 17408B < 32KB
    __syncthreads();         // all waves done with As/Bs fragments
#pragma unroll
    for (int i = 0; i < 2; ++i)
#pragma unroll
      for (int j = 0; j < 4; ++j)
#pragma unroll
        for (int r = 0; r < 4; ++r)
          tr[(j * 16 + lmod) * 136 + w * 32 + i * 16 + ldiv * 4 + r] =
              (__bf16)acc[i][j][r];
    __syncthreads();
    int col = t >> 2;
    int rseg = (t & 3) * 32;
    const __bf16* src = tr + col * 136 + rseg;
    __bf16* dst = Vt + ((size_t)kvh * 64 + col) * 2048 + bm * 128 + rseg;
#pragma unroll
    for (int c = 0; c < 4; ++c)
      *(bf16x8*)(dst + c * 8) = *(const bf16x8*)(src + c * 8);
  }
}

// ---------------------------------------------------------------- flash attention v11
// Triangle-fold: block (h, b) processes q-tile b (b+1 kv tiles) THEN q-tile 31-b
// (32-b kv tiles) = exactly 33 tile-units for EVERY block -> zero tail, steady
// 8 waves/CU. Core = v6: QBLK=64, 4 waves x 16 q rows, KVBLK=64 dbuf, swapped
// QK^T, pi-permuted K staging (P regs = PV A-frag), shift-free softmax.
__global__ __launch_bounds__(256) void attn_fwd(const __bf16* __restrict__ qkv,
                                                const __bf16* __restrict__ Kr,
                                                const __bf16* __restrict__ Vt,
                                                __bf16* __restrict__ O) {
  const int S = 2048, LDQ = 3072;
  int h = blockIdx.x;
  int b = blockIdx.y;  // 0..15
  int kvh = h >> 2;
  int t = threadIdx.x;
  int lane = t & 63, w = t >> 6;  // 4 waves
  int lmod = lane & 15, ldiv = lane >> 4;

  __shared__ alignas(16) __bf16 KV[2][2][4096];  // [buf][K/V][row*64+col], 32KB

  const __bf16* Kg = Kr + (size_t)kvh * S * 64;
  const __bf16* Vg = Vt + (size_t)kvh * 64 * S;
  int srow8 = lane >> 3;          // row-within-8 of chunk
  int schk = (lane & 7) ^ srow8;  // swizzled in-row 16B-chunk index

#define STAGE(buf, ks)                                                            \
  {                                                                               \
    __bf16* kb = &KV[buf][0][0];                                                  \
    __bf16* vb = &KV[buf][1][0];                                                  \
    _Pragma("unroll") for (int c = 0; c < 2; ++c) {                               \
      int c1kb = w * 2 + c;                                                       \
      int rr = c1kb * 8 + srow8;                                                  \
      int rrg = (rr & 0x23) | ((rr & 0x0C) << 1) | ((rr & 0x10) >> 2);            \
      gload_lds16(Kg + (size_t)((ks) + rrg) * 64 + schk * 8, kb + c1kb * 512);    \
      gload_lds16(Vg + (size_t)rr * S + (ks) + schk * 8, vb + c1kb * 512);        \
    }                                                                             \
  }

  int r7 = lmod & 7;
  int ca = ldiv ^ r7;        // swizzled chunk, k-slots 0..31 half
  int cb = (4 + ldiv) ^ r7;  // k-slots 32..63 half

#pragma unroll
  for (int seg = 0; seg < 2; ++seg) {
    int qt = seg ? (31 - b) : b;
    int nkt = qt + 1;
    int R0 = qt * 64 + w * 16;  // this wave's 16 q rows

    const __bf16* qp = qkv + (size_t)(R0 + lmod) * LDQ + h * 64 + ldiv * 8;
    bf16x8 qf0 = *(const bf16x8*)qp;
    bf16x8 qf1 = *(const bf16x8*)(qp + 32);

    f32x4 acc[4] = {};
    f32x4 lacc = {};

    __syncthreads();  // protect LDS reuse across segments
    STAGE(0, 0);

    int cur = 0;
    for (int kt = 0; kt < nkt; ++kt) {
      int ks = kt * 64;
      __syncthreads();  // drains own gload vmcnt (issued one compute-phase ago)
      if (kt + 1 < nkt) STAGE(cur ^ 1, ks + 64);
      const __bf16* Ksb = &KV[cur][0][0];
      const __bf16* Vsb = &KV[cur][1][0];

      // ---- QK^T (swapped): reg (t16,r) of lane (q=lmod,d=ldiv) holds score for
      // global k = ks + 32*(t16>>1) + 4*(t16&1) + 8*d + r (pi-permuted staging).
      f32x4 st[4] = {};
      __builtin_amdgcn_s_setprio(1);
#pragma unroll
      for (int t16 = 0; t16 < 4; ++t16) {
        int row = t16 * 16 + lmod;
        bf16x8 kf0 = *(const bf16x8*)(Ksb + row * 64 + ca * 8);
        bf16x8 kf1 = *(const bf16x8*)(Ksb + row * 64 + cb * 8);
        st[t16] = MFMA16(kf0, qf0, st[t16]);
        st[t16] = MFMA16(kf1, qf1, st[t16]);
      }
      __builtin_amdgcn_s_setprio(0);

      if (kt == nkt - 1) {  // diagonal tile: causal mask (permuted k formula)
        int qq = R0 + lmod;
#pragma unroll
        for (int t16 = 0; t16 < 4; ++t16) {
          int kk = ks + (t16 >> 1) * 32 + (t16 & 1) * 4 + ldiv * 8;
#pragma unroll
          for (int r = 0; r < 4; ++r)
            st[t16][r] = (kk + r) <= qq ? st[t16][r] : -1e30f;
        }
      }

      // V fragments
      bf16x8 vf[8];
#pragma unroll
      for (int g2 = 0; g2 < 4; ++g2) {
        int row = g2 * 16 + lmod;
        vf[g2] = *(const bf16x8*)(Vsb + row * 64 + ca * 8);
        vf[4 + g2] = *(const bf16x8*)(Vsb + row * 64 + cb * 8);
      }

      // ---- shift-free softmax: p = exp2(st); per-lane partial sums
#pragma unroll
      for (int t16 = 0; t16 < 4; ++t16)
#pragma unroll
        for (int r = 0; r < 4; ++r) {
          float pv = __builtin_amdgcn_exp2f(st[t16][r]);
          st[t16][r] = pv;
          lacc[r] += pv;
        }

      // pack P: registers are already in PV A-fragment order (pi staging)
      u32x4 av0, av1;
      av0[0] = pk2(st[0][0], st[0][1]);
      av0[1] = pk2(st[0][2], st[0][3]);
      av0[2] = pk2(st[1][0], st[1][1]);
      av0[3] = pk2(st[1][2], st[1][3]);
      av1[0] = pk2(st[2][0], st[2][1]);
      av1[1] = pk2(st[2][2], st[2][3]);
      av1[2] = pk2(st[3][0], st[3][1]);
      av1[3] = pk2(st[3][2], st[3][3]);
      bf16x8 pa0 = __builtin_bit_cast(bf16x8, av0);
      bf16x8 pa1 = __builtin_bit_cast(bf16x8, av1);

      __builtin_amdgcn_s_setprio(1);
#pragma unroll
      for (int g2 = 0; g2 < 4; ++g2) {
        acc[g2] = MFMA16(pa0, vf[g2], acc[g2]);
        acc[g2] = MFMA16(pa1, vf[4 + g2], acc[g2]);
      }
      __builtin_amdgcn_s_setprio(0);
      cur ^= 1;
    }

    // epilogue: reduce l across lanes once, then normalize
    {
      float lsum = lacc[0] + lacc[1] + lacc[2] + lacc[3];
      lsum += __shfl_xor(lsum, 16);
      lsum += __shfl_xor(lsum, 32);
      float linv[4];
#pragma unroll
      for (int r = 0; r < 4; ++r) {
        float lq = __shfl(lsum, ldiv * 4 + r);
        linv[r] = 1.0f / lq;
      }
#pragma unroll
      for (int g2 = 0; g2 < 4; ++g2)
#pragma unroll
        for (int r = 0; r < 4; ++r)
          O[(size_t)(R0 + ldiv * 4 + r) * 2048 + h * 64 + g2 * 16 + lmod] =
              (__bf16)(acc[g2][r] * linv[r]);
    }
  }
}

// ---------------------------------------------------------------- launch
extern "C" void kernel_launch(void* const* d_in, const int* in_sizes, int n_in,
                              void* d_out, int out_size, void* d_ws, size_t ws_size,
                              hipStream_t stream) {
  const float* x = (const float*)d_in[0];
  const float* cosb = (const float*)d_in[1];
  const float* sinb = (const float*)d_in[2];
  const float* wqkv = (const float*)d_in[3];
  const float* wo = (const float*)d_in[4];
  float* out = (float*)d_out;

  char* ws = (char*)d_ws;
  __bf16* xb    = (__bf16*)(ws + 0);
  __bf16* wqkvT = (__bf16*)(ws + 8388608);
  __bf16* woT   = (__bf16*)(ws + 20971520);
  __bf16* qkvb  = (__bf16*)(ws + 29360128);
  __bf16* Krb   = (__bf16*)(ws + 41943040);
  __bf16* Vtb   = (__bf16*)(ws + 44040192);
  __bf16* attnb = (__bf16*)(ws + 46137344);

  prep<<<6656, 256, 0, stream>>>(x, xb, wqkv, wqkvT, wo, woT);
  gemm_qkv<<<dim3(48, 16), 256, 0, stream>>>(xb, wqkvT, qkvb, Krb, Vtb,
                                             cosb, sinb, 2048, 2048);
  attn_fwd<<<dim3(32, 16), 256, 0, stream>>>(qkvb, Krb, Vtb, attnb);
  gemm64<float><<<dim3(32, 16), 256, 0, stream>>>(attnb, woT, out, 2048, 2048, 2048);
}